// Round 6
// baseline (4530.264 us; speedup 1.0000x reference)
//
#include <hip/hip_runtime.h>
#include <hip/hip_bf16.h>
#include <float.h>
#include <math.h>

#define BN   4096
#define DD   112
#define HH   512
#define G3   1536
#define CW   536
#define HIDD 512

typedef __attribute__((ext_vector_type(8))) short short8;
typedef __attribute__((ext_vector_type(4))) float float4v;

__device__ __forceinline__ unsigned short f2bf(float x) {
    __hip_bfloat16 h = __float2bfloat16(x);
    return *(unsigned short*)&h;
}

// ---------------- materialize const = [c | b | m]  (B x 536) ----------------
__global__ void build_const(const float* __restrict__ c, const float* __restrict__ b,
                            const float* __restrict__ m, float* __restrict__ out) {
    int idx = blockIdx.x * blockDim.x + threadIdx.x;
    if (idx >= BN * CW) return;
    int row = idx / CW, col = idx - row * CW;
    float v;
    if (col < 312)      v = c[row * 312 + col];
    else if (col < 424) v = b[row * 112 + (col - 312)];
    else                v = m[row * 112 + (col - 424)];
    out[idx] = v;
}

// ---------------- C[M,N] = A[M,536] @ W[536,N] + bias (fp32 exact) ----------------
__global__ __launch_bounds__(256) void gemm_bias(const float* __restrict__ A,
        const float* __restrict__ W, const float* __restrict__ bias,
        float* __restrict__ C, int N) {
    __shared__ float As[8][64];
    __shared__ float Ws[8][64];
    const int tid = threadIdx.x;
    const int tx = tid & 15, ty = tid >> 4;
    const int rowBase = blockIdx.x * 64, colBase = blockIdx.y * 64;
    float acc[4][4] = {};
    for (int kb = 0; kb < CW; kb += 8) {
        int l = tid * 2;
        {
            int i = l >> 3, j = l & 7;
            As[j][i] = A[(rowBase + i) * CW + kb + j];
            int i2 = (l + 1) >> 3, j2 = (l + 1) & 7;
            As[j2][i2] = A[(rowBase + i2) * CW + kb + j2];
        }
        {
            int j = l >> 6, n = l & 63;
            Ws[j][n] = W[(kb + j) * N + colBase + n];
            int j2 = (l + 1) >> 6, n2 = (l + 1) & 63;
            Ws[j2][n2] = W[(kb + j2) * N + colBase + n2];
        }
        __syncthreads();
#pragma unroll
        for (int k = 0; k < 8; ++k) {
            float av[4], wv[4];
#pragma unroll
            for (int i = 0; i < 4; ++i) av[i] = As[k][ty * 4 + i];
#pragma unroll
            for (int j = 0; j < 4; ++j) wv[j] = Ws[k][tx * 4 + j];
#pragma unroll
            for (int i = 0; i < 4; ++i)
#pragma unroll
                for (int j = 0; j < 4; ++j) acc[i][j] += av[i] * wv[j];
        }
        __syncthreads();
    }
#pragma unroll
    for (int i = 0; i < 4; ++i) {
        int r = rowBase + ty * 4 + i;
#pragma unroll
        for (int j = 0; j < 4; ++j) {
            int cc = colBase + tx * 4 + j;
            C[r * N + cc] = acc[i][j] + bias[cc];
        }
    }
}

// ---------------- mask = descending sort of m*(1-b) per row ----------------
__global__ void sort_mask(const float* __restrict__ b, const float* __restrict__ m,
                          float* __restrict__ maskbuf) {
    __shared__ float s[128];
    const int row = blockIdx.x, t = threadIdx.x;
    float v = -FLT_MAX;
    if (t < DD) v = m[row * DD + t] * (1.0f - b[row * DD + t]);
    s[t] = v;
    __syncthreads();
    for (int k = 2; k <= 128; k <<= 1) {
        for (int j = k >> 1; j > 0; j >>= 1) {
            int ixj = t ^ j;
            if (ixj > t) {
                bool up = ((t & k) == 0);
                float a = s[t], bb = s[ixj];
                if ((a > bb) == up) { s[t] = bb; s[ixj] = a; }
            }
            __syncthreads();
        }
    }
    if (t < DD) maskbuf[row * DD + t] = s[127 - t];
}

// ---------------- pack weight [K][N] -> MFMA B-fragments ----------------
__global__ void pack_w(const float* __restrict__ src, unsigned short* __restrict__ dst,
                       int kchunks, int ldn, int ncols) {
    int bid = blockIdx.x;
    int nt = bid / kchunks, kc = bid - nt * kchunks;
    int lane = threadIdx.x;
    int quad = lane >> 4, l16 = lane & 15;
    int n = nt * 16 + l16;
    unsigned short v[8];
#pragma unroll
    for (int j = 0; j < 8; ++j) {
        int k = kc * 32 + quad * 8 + j;
        float f = (n < ncols) ? src[(size_t)k * ldn + n] : 0.0f;
        v[j] = f2bf(f);
    }
    unsigned short* p = dst + ((size_t)bid * 64 + lane) * 8;
#pragma unroll
    for (int j = 0; j < 8; ++j) p[j] = v[j];
}

// ---------------- persistent GRU + MLP head + MDN logp (bf16 MFMA) ----------------
// 256 blocks x 16 rows, 1024 threads = 16 waves.
// T-chunked: gates twice (dbuf h), then head batched over 2 steps (W0h/W1/W2
// fragments loaded once per 2 steps). fp32 h master in regs; bf16 mirrors in LDS.
__global__ __launch_bounds__(1024, 4) void gru_mfma(
    const float* __restrict__ z, const float* __restrict__ Wih,
    const float* __restrict__ bhh, const float* __restrict__ b1,
    const float* __restrict__ b2,
    const float* __restrict__ gi_const, const float* __restrict__ mlp_const,
    const float* __restrict__ maskbuf,
    const unsigned short* __restrict__ WhhP, const unsigned short* __restrict__ W0hP,
    const unsigned short* __restrict__ W1P, const unsigned short* __restrict__ W2P,
    float* __restrict__ out)
{
    __shared__ unsigned short h_bf0[16 * 520];  // h at chunk start / h2(t+1)
    __shared__ unsigned short h_bf1[16 * 520];  // h2(t)
    __shared__ unsigned short a_bf[32 * 520];   // a1 then a2 for both steps
    __shared__ float pp[16 * 512];              // W2 partials: [wave][nt][lane][rg]
    __shared__ float zbuf[113 * 16];            // zbuf[tt*16+r] = z_prev at step tt
    __shared__ float mbuf[16 * 112];            // mask per (row,t)

    const int tid = threadIdx.x;
    const int wave = tid >> 6, lane = tid & 63;
    const int quad = lane >> 4, l16 = lane & 15;
    const int pr = tid >> 5, pc = tid & 31;     // MDN: pr = mt*16+row (0..31)
    const int rowBase = blockIdx.x * 16;

    for (int idx = tid; idx < 16 * 520; idx += 1024) h_bf0[idx] = 0;
    for (int idx = tid; idx < 113 * 16; idx += 1024) {
        int tt = idx >> 4, r = idx & 15;
        zbuf[idx] = (tt == 0) ? -1.0f : z[(rowBase + r) * DD + tt - 1];
    }
    for (int idx = tid; idx < 16 * 112; idx += 1024) {
        int r = idx / DD, tt = idx - r * DD;
        mbuf[idx] = maskbuf[(rowBase + r) * DD + tt];
    }

    // hoisted per-lane constants, C-layout (col = lane&15, row m = quad*4+rg)
    int hcol[2];
    float wz0[2], wz1[2], wz2[2], bh2r[2], b1c[2];
    float gic0[2][4], gic1[2][4], gic2[2][4], mlc[2][4];
    float h_own[2][4];
#pragma unroll
    for (int i = 0; i < 2; ++i) {
        int tile = wave + 16 * i;
        int hc = tile * 16 + l16;
        hcol[i] = hc;
        wz0[i] = Wih[hc]; wz1[i] = Wih[512 + hc]; wz2[i] = Wih[1024 + hc];
        float bh0 = bhh[hc], bh1 = bhh[512 + hc];
        bh2r[i] = bhh[1024 + hc];
        b1c[i] = b1[hc];
#pragma unroll
        for (int rg = 0; rg < 4; ++rg) {
            int m = quad * 4 + rg;
            const float* g = gi_const + (size_t)(rowBase + m) * G3;
            gic0[i][rg] = g[hc] + bh0;
            gic1[i][rg] = g[512 + hc] + bh1;
            gic2[i][rg] = g[1024 + hc];
            mlc[i][rg] = mlp_const[(size_t)(rowBase + m) * HIDD + hc];
            h_own[i][rg] = 0.0f;
        }
    }
    const float b2v = (pc < 30) ? b2[pc] : 0.0f;
    // MDN indexing: mt = pr>>4, row m = pr&15
    const int mdn_mt = pr >> 4, mdn_m = pr & 15;
    const int ppofs = (mdn_mt * 8) * 512 + (pc >> 4) * 256
                      + ((mdn_m >> 2) * 16 + (pc & 15)) * 4 + (mdn_m & 3);

    const short8* WhhF = (const short8*)WhhP;
    const short8* W0hF = (const short8*)W0hP;
    const short8* W1F  = (const short8*)W1P;
    const short8* W2F  = (const short8*)W2P;

    float llacc = 0.0f;
    __syncthreads();

    for (int t = 0; t < DD; t += 2) {
#pragma unroll
        for (int step = 0; step < 2; ++step) {
            const unsigned short* hsrc = step == 0 ? h_bf0 : h_bf1;
            unsigned short* hdst = step == 0 ? h_bf1 : h_bf0;
            // ---- gates: h @ Whh, C init = gi_const(+bhh) ----
            float4v accR[2], accU[2], accN[2];
#pragma unroll
            for (int i = 0; i < 2; ++i) {
                accR[i] = (float4v){gic0[i][0], gic0[i][1], gic0[i][2], gic0[i][3]};
                accU[i] = (float4v){gic1[i][0], gic1[i][1], gic1[i][2], gic1[i][3]};
                accN[i] = (float4v){0.f, 0.f, 0.f, 0.f};
            }
#pragma unroll 4
            for (int kc = 0; kc < 16; ++kc) {
                short8 af = *(const short8*)&hsrc[l16 * 520 + kc * 32 + quad * 8];
#pragma unroll
                for (int i = 0; i < 2; ++i) {
                    int tile = wave + 16 * i;
                    accR[i] = __builtin_amdgcn_mfma_f32_16x16x32_bf16(af, WhhF[(tile * 16 + kc) * 64 + lane], accR[i], 0, 0, 0);
                    accU[i] = __builtin_amdgcn_mfma_f32_16x16x32_bf16(af, WhhF[((tile + 32) * 16 + kc) * 64 + lane], accU[i], 0, 0, 0);
                    accN[i] = __builtin_amdgcn_mfma_f32_16x16x32_bf16(af, WhhF[((tile + 64) * 16 + kc) * 64 + lane], accN[i], 0, 0, 0);
                }
            }
            // nonlin -> write OTHER buffer (no barrier needed before writes)
#pragma unroll
            for (int i = 0; i < 2; ++i) {
#pragma unroll
                for (int rg = 0; rg < 4; ++rg) {
                    int m = quad * 4 + rg;
                    float zt = zbuf[(t + step) * 16 + m];
                    float r = 1.0f / (1.0f + __expf(-(accR[i][rg] + zt * wz0[i])));
                    float u = 1.0f / (1.0f + __expf(-(accU[i][rg] + zt * wz1[i])));
                    float xn = gic2[i][rg] + zt * wz2[i] + r * (accN[i][rg] + bh2r[i]);
                    float n = 1.0f - 2.0f / (__expf(2.0f * xn) + 1.0f);
                    float h2 = (1.0f - u) * n + u * h_own[i][rg];
                    h_own[i][rg] = h2;
                    hdst[m * 520 + hcol[i]] = f2bf(h2);
                }
            }
            __syncthreads();  // S1/S2: h2(step) mirror ready
        }
        // ---- a1 = tanh(h2 @ W0h + mlp_const), both steps share B fragments ----
        // mt=0 <- h_bf1 (h2(t)), mt=1 <- h_bf0 (h2(t+1))
        float4v acc1[2][2];
#pragma unroll
        for (int i = 0; i < 2; ++i)
#pragma unroll
            for (int mt = 0; mt < 2; ++mt)
                acc1[i][mt] = (float4v){mlc[i][0], mlc[i][1], mlc[i][2], mlc[i][3]};
#pragma unroll 4
        for (int kc = 0; kc < 16; ++kc) {
            short8 af0 = *(const short8*)&h_bf1[l16 * 520 + kc * 32 + quad * 8];
            short8 af1 = *(const short8*)&h_bf0[l16 * 520 + kc * 32 + quad * 8];
#pragma unroll
            for (int i = 0; i < 2; ++i) {
                short8 bf = W0hF[((wave + 16 * i) * 16 + kc) * 64 + lane];
                acc1[i][0] = __builtin_amdgcn_mfma_f32_16x16x32_bf16(af0, bf, acc1[i][0], 0, 0, 0);
                acc1[i][1] = __builtin_amdgcn_mfma_f32_16x16x32_bf16(af1, bf, acc1[i][1], 0, 0, 0);
            }
        }
#pragma unroll
        for (int i = 0; i < 2; ++i)
#pragma unroll
            for (int mt = 0; mt < 2; ++mt)
#pragma unroll
                for (int rg = 0; rg < 4; ++rg) {
                    int m = quad * 4 + rg;
                    float x = acc1[i][mt][rg];
                    a_bf[(mt * 16 + m) * 520 + hcol[i]] = f2bf(1.0f - 2.0f / (__expf(2.0f * x) + 1.0f));
                }
        __syncthreads();  // S3: a1 ready (both steps)
        // ---- a2 = tanh(a1 @ W1 + b1) ----
        float4v acc2[2][2];
#pragma unroll
        for (int i = 0; i < 2; ++i)
#pragma unroll
            for (int mt = 0; mt < 2; ++mt)
                acc2[i][mt] = (float4v){b1c[i], b1c[i], b1c[i], b1c[i]};
#pragma unroll 4
        for (int kc = 0; kc < 16; ++kc) {
            short8 af0 = *(const short8*)&a_bf[l16 * 520 + kc * 32 + quad * 8];
            short8 af1 = *(const short8*)&a_bf[(16 + l16) * 520 + kc * 32 + quad * 8];
#pragma unroll
            for (int i = 0; i < 2; ++i) {
                short8 bf = W1F[((wave + 16 * i) * 16 + kc) * 64 + lane];
                acc2[i][0] = __builtin_amdgcn_mfma_f32_16x16x32_bf16(af0, bf, acc2[i][0], 0, 0, 0);
                acc2[i][1] = __builtin_amdgcn_mfma_f32_16x16x32_bf16(af1, bf, acc2[i][1], 0, 0, 0);
            }
        }
        __syncthreads();  // S4: all reads of a1 done
#pragma unroll
        for (int i = 0; i < 2; ++i)
#pragma unroll
            for (int mt = 0; mt < 2; ++mt)
#pragma unroll
                for (int rg = 0; rg < 4; ++rg) {
                    int m = quad * 4 + rg;
                    float x = acc2[i][mt][rg];
                    a_bf[(mt * 16 + m) * 520 + hcol[i]] = f2bf(1.0f - 2.0f / (__expf(2.0f * x) + 1.0f));
                }
        __syncthreads();  // S5: a2 ready
        // ---- p = a2 @ W2 + b2 : wave w -> mt=w>>3, kc pair (w&7)*2,+1 ----
        {
            const int mtw = wave >> 3;
            float4v ap0 = (float4v){0.f, 0.f, 0.f, 0.f}, ap1 = (float4v){0.f, 0.f, 0.f, 0.f};
#pragma unroll
            for (int kk = 0; kk < 2; ++kk) {
                int kc = (wave & 7) * 2 + kk;
                short8 af = *(const short8*)&a_bf[(mtw * 16 + l16) * 520 + kc * 32 + quad * 8];
                ap0 = __builtin_amdgcn_mfma_f32_16x16x32_bf16(af, W2F[(0 * 16 + kc) * 64 + lane], ap0, 0, 0, 0);
                ap1 = __builtin_amdgcn_mfma_f32_16x16x32_bf16(af, W2F[(1 * 16 + kc) * 64 + lane], ap1, 0, 0, 0);
            }
#pragma unroll
            for (int rg = 0; rg < 4; ++rg) {
                pp[wave * 512 + 0 * 256 + lane * 4 + rg] = ap0[rg];
                pp[wave * 512 + 1 * 256 + lane * 4 + rg] = ap1[rg];
            }
        }
        __syncthreads();  // S6: partials ready
        // ---- reduce partials + MDN logsumexp, all 16 waves (32 row-slots) ----
        {
            float pv = b2v;
#pragma unroll
            for (int w = 0; w < 8; ++w) pv += pp[ppofs + w * 512];
            const int half = lane & 32;
            float meanv = __shfl(pv, half + ((pc + 10) & 31), 64);
            float lsigv = __shfl(pv, half + ((pc + 20) & 31), 64);
            float e1, e2;
            if (pc < 10) {
                float ztar = zbuf[(t + mdn_mt + 1) * 16 + mdn_m];
                float invs = __expf(-lsigv);
                float dd = (ztar - meanv) * invs;
                e1 = -0.5f * dd * dd - lsigv - 0.91893853320467274f + pv;
                e2 = pv;
            } else { e1 = -FLT_MAX; e2 = -FLT_MAX; }
            float m1 = e1, m2 = e2;
#pragma unroll
            for (int off = 16; off > 0; off >>= 1) {
                m1 = fmaxf(m1, __shfl_xor(m1, off, 64));
                m2 = fmaxf(m2, __shfl_xor(m2, off, 64));
            }
            float s1 = (pc < 10) ? __expf(e1 - m1) : 0.0f;
            float s2 = (pc < 10) ? __expf(e2 - m2) : 0.0f;
#pragma unroll
            for (int off = 16; off > 0; off >>= 1) {
                s1 += __shfl_xor(s1, off, 64);
                s2 += __shfl_xor(s2, off, 64);
            }
            float ll = (m1 + __logf(s1)) - (m2 + __logf(s2));
            llacc += ll * mbuf[mdn_m * 112 + t + mdn_mt];
        }
        // next chunk's first writes (h_bf1) are ordered behind next S1; pp/a_bf
        // rewrites are >=2 barriers away -> no extra barrier needed here
        __syncthreads();
    }
    // combine the two step-parity partials per row
    if (pc == 0) pp[pr] = llacc;
    __syncthreads();
    if (tid < 16) out[rowBase + tid] = pp[tid] + pp[16 + tid];
}

extern "C" void kernel_launch(void* const* d_in, const int* in_sizes, int n_in,
                              void* d_out, int out_size, void* d_ws, size_t ws_size,
                              hipStream_t stream) {
    const float* z   = (const float*)d_in[0];
    const float* c   = (const float*)d_in[1];
    const float* b   = (const float*)d_in[2];
    const float* m   = (const float*)d_in[3];
    const float* Wih = (const float*)d_in[4];
    const float* Whh = (const float*)d_in[5];
    const float* bih = (const float*)d_in[6];
    const float* bhh = (const float*)d_in[7];
    const float* W0  = (const float*)d_in[8];
    const float* b0  = (const float*)d_in[9];
    const float* W1  = (const float*)d_in[10];
    const float* b1  = (const float*)d_in[11];
    const float* W2  = (const float*)d_in[12];
    const float* b2  = (const float*)d_in[13];
    float* out = (float*)d_out;

    float* ws        = (float*)d_ws;
    float* constbuf  = ws;                                   // B*536
    float* gi_const  = constbuf + (size_t)BN * CW;           // B*1536
    float* mlp_const = gi_const + (size_t)BN * G3;           // B*512
    float* maskbuf   = mlp_const + (size_t)BN * HIDD;        // B*112
    unsigned short* WhhP = (unsigned short*)(maskbuf + (size_t)BN * DD);
    unsigned short* W0hP = WhhP + (size_t)96 * 16 * 512;
    unsigned short* W1P  = W0hP + (size_t)32 * 16 * 512;
    unsigned short* W2P  = W1P  + (size_t)32 * 16 * 512;

    build_const<<<(BN * CW + 255) / 256, 256, 0, stream>>>(c, b, m, constbuf);
    dim3 g1(BN / 64, G3 / 64);
    gemm_bias<<<g1, 256, 0, stream>>>(constbuf, Wih + G3, bih, gi_const, G3);
    dim3 g2(BN / 64, HIDD / 64);
    gemm_bias<<<g2, 256, 0, stream>>>(constbuf, W0 + (size_t)HH * HIDD, b0, mlp_const, HIDD);
    sort_mask<<<BN, 128, 0, stream>>>(b, m, maskbuf);

    pack_w<<<96 * 16, 64, 0, stream>>>(Whh, WhhP, 16, G3, G3);
    pack_w<<<32 * 16, 64, 0, stream>>>(W0,  W0hP, 16, HIDD, HIDD);
    pack_w<<<32 * 16, 64, 0, stream>>>(W1,  W1P,  16, HIDD, HIDD);
    pack_w<<<2 * 16, 64, 0, stream>>>(W2,  W2P,  16, 30, 30);

    gru_mfma<<<BN / 16, 1024, 0, stream>>>(z, Wih, bhh, b1, b2, gi_const, mlp_const,
                                           maskbuf, WhhP, W0hP, W1P, W2P, out);
}

// Round 7
// 3152.048 us; speedup vs baseline: 1.4372x; 1.4372x over previous
//
#include <hip/hip_runtime.h>
#include <hip/hip_bf16.h>
#include <float.h>
#include <math.h>

#define BN   4096
#define DD   112
#define HH   512
#define G3   1536
#define CW   536
#define HIDD 512

typedef __attribute__((ext_vector_type(8))) short short8;
typedef __attribute__((ext_vector_type(4))) float float4v;

__device__ __forceinline__ unsigned short f2bf(float x) {
    __hip_bfloat16 h = __float2bfloat16(x);
    return *(unsigned short*)&h;
}

// ---------------- materialize const = [c | b | m]  (B x 536) ----------------
__global__ void build_const(const float* __restrict__ c, const float* __restrict__ b,
                            const float* __restrict__ m, float* __restrict__ out) {
    int idx = blockIdx.x * blockDim.x + threadIdx.x;
    if (idx >= BN * CW) return;
    int row = idx / CW, col = idx - row * CW;
    float v;
    if (col < 312)      v = c[row * 312 + col];
    else if (col < 424) v = b[row * 112 + (col - 312)];
    else                v = m[row * 112 + (col - 424)];
    out[idx] = v;
}

// ---------------- generic fp32 GEMM + bias (row-major out) ----------------
__global__ __launch_bounds__(256) void gemm_bias(const float* __restrict__ A,
        const float* __restrict__ W, const float* __restrict__ bias,
        float* __restrict__ C, int N) {
    __shared__ float As[8][64];
    __shared__ float Ws[8][64];
    const int tid = threadIdx.x;
    const int tx = tid & 15, ty = tid >> 4;
    const int rowBase = blockIdx.x * 64, colBase = blockIdx.y * 64;
    float acc[4][4] = {};
    for (int kb = 0; kb < CW; kb += 8) {
        int l = tid * 2;
        {
            int i = l >> 3, j = l & 7;
            As[j][i] = A[(rowBase + i) * CW + kb + j];
            int i2 = (l + 1) >> 3, j2 = (l + 1) & 7;
            As[j2][i2] = A[(rowBase + i2) * CW + kb + j2];
        }
        {
            int j = l >> 6, n = l & 63;
            Ws[j][n] = W[(kb + j) * N + colBase + n];
            int j2 = (l + 1) >> 6, n2 = (l + 1) & 63;
            Ws[j2][n2] = W[(kb + j2) * N + colBase + n2];
        }
        __syncthreads();
#pragma unroll
        for (int k = 0; k < 8; ++k) {
            float av[4], wv[4];
#pragma unroll
            for (int i = 0; i < 4; ++i) av[i] = As[k][ty * 4 + i];
#pragma unroll
            for (int j = 0; j < 4; ++j) wv[j] = Ws[k][tx * 4 + j];
#pragma unroll
            for (int i = 0; i < 4; ++i)
#pragma unroll
                for (int j = 0; j < 4; ++j) acc[i][j] += av[i] * wv[j];
        }
        __syncthreads();
    }
#pragma unroll
    for (int i = 0; i < 4; ++i) {
        int r = rowBase + ty * 4 + i;
#pragma unroll
        for (int j = 0; j < 4; ++j) {
            int cc = colBase + tx * 4 + j;
            C[r * N + cc] = acc[i][j] + bias[cc];
        }
    }
}

// ---------------- gi_const GEMM -> packed per-(ablock,wave,lane) C-layout (M=32) ----------------
__global__ __launch_bounds__(256) void gemm_gicP(const float* __restrict__ A,
        const float* __restrict__ W, const float* __restrict__ bih,
        const float* __restrict__ bhh, float* __restrict__ gicP) {
    const int N = G3;
    __shared__ float As[8][64];
    __shared__ float Ws[8][64];
    const int tid = threadIdx.x;
    const int tx = tid & 15, ty = tid >> 4;
    const int rowBase = blockIdx.x * 64, colBase = blockIdx.y * 64;
    float acc[4][4] = {};
    for (int kb = 0; kb < CW; kb += 8) {
        int l = tid * 2;
        {
            int i = l >> 3, j = l & 7;
            As[j][i] = A[(rowBase + i) * CW + kb + j];
            int i2 = (l + 1) >> 3, j2 = (l + 1) & 7;
            As[j2][i2] = A[(rowBase + i2) * CW + kb + j2];
        }
        {
            int j = l >> 6, n = l & 63;
            Ws[j][n] = W[(kb + j) * N + colBase + n];
            int j2 = (l + 1) >> 6, n2 = (l + 1) & 63;
            Ws[j2][n2] = W[(kb + j2) * N + colBase + n2];
        }
        __syncthreads();
#pragma unroll
        for (int k = 0; k < 8; ++k) {
            float av[4], wv[4];
#pragma unroll
            for (int i = 0; i < 4; ++i) av[i] = As[k][ty * 4 + i];
#pragma unroll
            for (int j = 0; j < 4; ++j) wv[j] = Ws[k][tx * 4 + j];
#pragma unroll
            for (int i = 0; i < 4; ++i)
#pragma unroll
                for (int j = 0; j < 4; ++j) acc[i][j] += av[i] * wv[j];
        }
        __syncthreads();
    }
#pragma unroll
    for (int i = 0; i < 4; ++i) {
        int r = rowBase + ty * 4 + i;
        int ablock = r >> 5, mrem = r & 31, mt = mrem >> 4, mm = mrem & 15;
        int quad = mm >> 2, rg = mm & 3;
#pragma unroll
        for (int j = 0; j < 4; ++j) {
            int cc = colBase + tx * 4 + j;
            int g = cc >> 9, nrem = cc & 511, tile = nrem >> 4, l16 = nrem & 15;
            int wv = tile & 15, ii = tile >> 4;
            size_t off = ((((size_t)(ablock * 16 + wv) * 2 + ii) * 2 + mt) * 3 + g) * 256
                         + (quad * 16 + l16) * 4 + rg;
            gicP[off] = acc[i][j] + bih[cc] + ((g < 2) ? bhh[cc] : 0.0f);
        }
    }
}

// ---------------- mask = descending sort of m*(1-b) per row ----------------
__global__ void sort_mask(const float* __restrict__ b, const float* __restrict__ m,
                          float* __restrict__ maskbuf) {
    __shared__ float s[128];
    const int row = blockIdx.x, t = threadIdx.x;
    float v = -FLT_MAX;
    if (t < DD) v = m[row * DD + t] * (1.0f - b[row * DD + t]);
    s[t] = v;
    __syncthreads();
    for (int k = 2; k <= 128; k <<= 1) {
        for (int j = k >> 1; j > 0; j >>= 1) {
            int ixj = t ^ j;
            if (ixj > t) {
                bool up = ((t & k) == 0);
                float a = s[t], bb = s[ixj];
                if ((a > bb) == up) { s[t] = bb; s[ixj] = a; }
            }
            __syncthreads();
        }
    }
    if (t < DD) maskbuf[row * DD + t] = s[127 - t];
}

// ---------------- pack weight [K][N] -> MFMA B-fragments ----------------
__global__ void pack_w(const float* __restrict__ src, unsigned short* __restrict__ dst,
                       int kchunks, int ldn, int ncols) {
    int bid = blockIdx.x;
    int nt = bid / kchunks, kc = bid - nt * kchunks;
    int lane = threadIdx.x;
    int quad = lane >> 4, l16 = lane & 15;
    int n = nt * 16 + l16;
    unsigned short v[8];
#pragma unroll
    for (int j = 0; j < 8; ++j) {
        int k = kc * 32 + quad * 8 + j;
        float f = (n < ncols) ? src[(size_t)k * ldn + n] : 0.0f;
        v[j] = f2bf(f);
    }
    unsigned short* p = dst + ((size_t)bid * 64 + lane) * 8;
#pragma unroll
    for (int j = 0; j < 8; ++j) p[j] = v[j];
}

// ================= KERNEL A: GRU recurrence only, M=32, writes h2(t) bf16 =================
// 128 blocks x 32 rows, 1024 threads = 16 waves. gic streamed from gicP (no hoist).
__global__ __launch_bounds__(1024, 4) void gru_rec(
    const float* __restrict__ z, const float* __restrict__ Wih,
    const float* __restrict__ bhh, const float* __restrict__ gicP,
    const unsigned short* __restrict__ WhhP, unsigned short* __restrict__ h2g)
{
    __shared__ unsigned short h_bf[32 * 520];
    __shared__ float zbuf[113 * 32];

    const int tid = threadIdx.x;
    const int wave = tid >> 6, lane = tid & 63;
    const int quad = lane >> 4, l16 = lane & 15;
    const int rowBase = blockIdx.x * 32;

    for (int idx = tid; idx < 32 * 520; idx += 1024) h_bf[idx] = 0;
    for (int idx = tid; idx < 113 * 32; idx += 1024) {
        int tt = idx >> 5, r = idx & 31;
        zbuf[idx] = (tt == 0) ? -1.0f : z[(size_t)(rowBase + r) * DD + tt - 1];
    }

    int hcol[2];
    float wz0[2], wz1[2], wz2[2], bh2r[2];
#pragma unroll
    for (int i = 0; i < 2; ++i) {
        int hc = (wave + 16 * i) * 16 + l16;
        hcol[i] = hc;
        wz0[i] = Wih[hc]; wz1[i] = Wih[512 + hc]; wz2[i] = Wih[1024 + hc];
        bh2r[i] = bhh[1024 + hc];
    }
    float h_own[2][2][4];
#pragma unroll
    for (int i = 0; i < 2; ++i)
#pragma unroll
        for (int mt = 0; mt < 2; ++mt)
#pragma unroll
            for (int rg = 0; rg < 4; ++rg) h_own[i][mt][rg] = 0.0f;

    const float* gicW = gicP + (size_t)(blockIdx.x * 16 + wave) * 12 * 256;
    const short8* WhhF = (const short8*)WhhP;
    __syncthreads();

    for (int t = 0; t < DD; ++t) {
        // acc init: r/u parts streamed from gicP (coalesced dwordx4, L2-hot)
        float4v acc[3][2][2];
#pragma unroll
        for (int i = 0; i < 2; ++i)
#pragma unroll
            for (int mt = 0; mt < 2; ++mt) {
                acc[0][i][mt] = *(const float4v*)(gicW + ((i * 2 + mt) * 3 + 0) * 256 + lane * 4);
                acc[1][i][mt] = *(const float4v*)(gicW + ((i * 2 + mt) * 3 + 1) * 256 + lane * 4);
                acc[2][i][mt] = (float4v){0.f, 0.f, 0.f, 0.f};
            }
#pragma unroll 4
        for (int kc = 0; kc < 16; ++kc) {
            short8 af[2];
#pragma unroll
            for (int mt = 0; mt < 2; ++mt)
                af[mt] = *(const short8*)&h_bf[(mt * 16 + l16) * 520 + kc * 32 + quad * 8];
#pragma unroll
            for (int i = 0; i < 2; ++i) {
                int tile = wave + 16 * i;
#pragma unroll
                for (int g = 0; g < 3; ++g) {
                    short8 bf = WhhF[((tile + 32 * g) * 16 + kc) * 64 + lane];
#pragma unroll
                    for (int mt = 0; mt < 2; ++mt)
                        acc[g][i][mt] = __builtin_amdgcn_mfma_f32_16x16x32_bf16(af[mt], bf, acc[g][i][mt], 0, 0, 0);
                }
            }
        }
        __syncthreads();  // S1: all A-frag reads done
#pragma unroll
        for (int i = 0; i < 2; ++i)
#pragma unroll
            for (int mt = 0; mt < 2; ++mt) {
                float4v gn = *(const float4v*)(gicW + ((i * 2 + mt) * 3 + 2) * 256 + lane * 4);
#pragma unroll
                for (int rg = 0; rg < 4; ++rg) {
                    int m = mt * 16 + quad * 4 + rg;
                    float zt = zbuf[t * 32 + m];
                    float r = 1.0f / (1.0f + __expf(-(acc[0][i][mt][rg] + zt * wz0[i])));
                    float u = 1.0f / (1.0f + __expf(-(acc[1][i][mt][rg] + zt * wz1[i])));
                    float xn = gn[rg] + zt * wz2[i] + r * (acc[2][i][mt][rg] + bh2r[i]);
                    float n = 1.0f - 2.0f / (__expf(2.0f * xn) + 1.0f);
                    float h2 = (1.0f - u) * n + u * h_own[i][mt][rg];
                    h_own[i][mt][rg] = h2;
                    h_bf[m * 520 + hcol[i]] = f2bf(h2);
                }
            }
        __syncthreads();  // S2: mirror complete
        // coalesced h2 slab store: thread -> 16 contiguous bf16
        {
            int flat = tid * 16;
            int r = flat >> 9, col = flat & 511;
            const uint4* src = (const uint4*)&h_bf[r * 520 + col];
            uint4 v0 = src[0], v1 = src[1];
            uint4* dst = (uint4*)&h2g[((size_t)(rowBase + r) * DD + t) * 512 + col];
            dst[0] = v0; dst[1] = v1;
        }
        // next overwrite of h_bf is after next S1 -> no extra barrier
    }
}

// ================= KERNEL B: MLP head + MDN over all (b,t) rows =================
// grid 14336 = 2048 (b-pairs) x 7 (t-groups of 16); 1024 threads = 16 waves.
// Block = 2 batch-rows x 16 timesteps (M=32). atomicAdd per-b partials into out.
__global__ __launch_bounds__(1024, 4) void head_mdn(
    const float* __restrict__ z, const float* __restrict__ b1,
    const float* __restrict__ b2, const float* __restrict__ mlp_const,
    const float* __restrict__ maskbuf, const unsigned short* __restrict__ h2g,
    const unsigned short* __restrict__ W0hP, const unsigned short* __restrict__ W1P,
    const unsigned short* __restrict__ W2P, float* __restrict__ out)
{
    __shared__ unsigned short h_bf[32 * 520];
    __shared__ unsigned short a_bf[32 * 520];
    __shared__ float pp[16 * 512];

    const int tid = threadIdx.x;
    const int wave = tid >> 6, lane = tid & 63;
    const int quad = lane >> 4, l16 = lane & 15;
    const int pr = tid >> 5, pc = tid & 31;
    const int bi = blockIdx.x / 7, ti = blockIdx.x - bi * 7;
    const int b0 = bi * 2, t0 = ti * 16;

    // stage h2 tile (rows: mt*16 + toff -> (b0+mt, t0+toff)), coalesced
    {
        int flat = tid * 16;
        int r = flat >> 9, col = flat & 511;
        int bb = b0 + (r >> 4), tt = t0 + (r & 15);
        const uint4* src = (const uint4*)&h2g[((size_t)bb * DD + tt) * 512 + col];
        uint4 v0 = src[0], v1 = src[1];
        uint4* dst = (uint4*)&h_bf[r * 520 + col];
        dst[0] = v0; dst[1] = v1;
    }
    int hcol[2];
    float b1c[2], mlc[2][2];
#pragma unroll
    for (int i = 0; i < 2; ++i) {
        int hc = (wave + 16 * i) * 16 + l16;
        hcol[i] = hc;
        b1c[i] = b1[hc];
#pragma unroll
        for (int mt = 0; mt < 2; ++mt) mlc[i][mt] = mlp_const[(size_t)(b0 + mt) * HIDD + hc];
    }
    const float b2v = (pc < 30) ? b2[pc] : 0.0f;
    const int mdn_mt = pr >> 4, mdn_m = pr & 15;   // batch-sub, t-offset
    const int ppofs = (mdn_mt * 8) * 512 + (pc >> 4) * 256
                      + ((mdn_m >> 2) * 16 + (pc & 15)) * 4 + (mdn_m & 3);

    const short8* W0hF = (const short8*)W0hP;
    const short8* W1F  = (const short8*)W1P;
    const short8* W2F  = (const short8*)W2P;
    __syncthreads();  // S0: h tile staged

    // ---- a1 = tanh(h2 @ W0h + mlc[b]) ----
    float4v acc1[2][2];
#pragma unroll
    for (int i = 0; i < 2; ++i)
#pragma unroll
        for (int mt = 0; mt < 2; ++mt)
            acc1[i][mt] = (float4v){mlc[i][mt], mlc[i][mt], mlc[i][mt], mlc[i][mt]};
#pragma unroll 4
    for (int kc = 0; kc < 16; ++kc) {
        short8 af0 = *(const short8*)&h_bf[l16 * 520 + kc * 32 + quad * 8];
        short8 af1 = *(const short8*)&h_bf[(16 + l16) * 520 + kc * 32 + quad * 8];
#pragma unroll
        for (int i = 0; i < 2; ++i) {
            short8 bf = W0hF[((wave + 16 * i) * 16 + kc) * 64 + lane];
            acc1[i][0] = __builtin_amdgcn_mfma_f32_16x16x32_bf16(af0, bf, acc1[i][0], 0, 0, 0);
            acc1[i][1] = __builtin_amdgcn_mfma_f32_16x16x32_bf16(af1, bf, acc1[i][1], 0, 0, 0);
        }
    }
#pragma unroll
    for (int i = 0; i < 2; ++i)
#pragma unroll
        for (int mt = 0; mt < 2; ++mt)
#pragma unroll
            for (int rg = 0; rg < 4; ++rg) {
                int m = mt * 16 + quad * 4 + rg;
                float x = acc1[i][mt][rg];
                a_bf[m * 520 + hcol[i]] = f2bf(1.0f - 2.0f / (__expf(2.0f * x) + 1.0f));
            }
    __syncthreads();  // S3: a1 ready
    // ---- a2 = tanh(a1 @ W1 + b1) ----
    float4v acc2[2][2];
#pragma unroll
    for (int i = 0; i < 2; ++i)
#pragma unroll
        for (int mt = 0; mt < 2; ++mt)
            acc2[i][mt] = (float4v){b1c[i], b1c[i], b1c[i], b1c[i]};
#pragma unroll 4
    for (int kc = 0; kc < 16; ++kc) {
        short8 af0 = *(const short8*)&a_bf[l16 * 520 + kc * 32 + quad * 8];
        short8 af1 = *(const short8*)&a_bf[(16 + l16) * 520 + kc * 32 + quad * 8];
#pragma unroll
        for (int i = 0; i < 2; ++i) {
            short8 bf = W1F[((wave + 16 * i) * 16 + kc) * 64 + lane];
            acc2[i][0] = __builtin_amdgcn_mfma_f32_16x16x32_bf16(af0, bf, acc2[i][0], 0, 0, 0);
            acc2[i][1] = __builtin_amdgcn_mfma_f32_16x16x32_bf16(af1, bf, acc2[i][1], 0, 0, 0);
        }
    }
    __syncthreads();  // S4: all reads of a1 done
#pragma unroll
    for (int i = 0; i < 2; ++i)
#pragma unroll
        for (int mt = 0; mt < 2; ++mt)
#pragma unroll
            for (int rg = 0; rg < 4; ++rg) {
                int m = mt * 16 + quad * 4 + rg;
                float x = acc2[i][mt][rg];
                a_bf[m * 520 + hcol[i]] = f2bf(1.0f - 2.0f / (__expf(2.0f * x) + 1.0f));
            }
    __syncthreads();  // S5: a2 ready
    // ---- p = a2 @ W2 + b2 : wave -> mt = w>>3, kc pair (w&7)*2..+1 ----
    {
        const int mtw = wave >> 3;
        float4v ap0 = (float4v){0.f, 0.f, 0.f, 0.f}, ap1 = (float4v){0.f, 0.f, 0.f, 0.f};
#pragma unroll
        for (int kk = 0; kk < 2; ++kk) {
            int kc = (wave & 7) * 2 + kk;
            short8 af = *(const short8*)&a_bf[(mtw * 16 + l16) * 520 + kc * 32 + quad * 8];
            ap0 = __builtin_amdgcn_mfma_f32_16x16x32_bf16(af, W2F[(0 * 16 + kc) * 64 + lane], ap0, 0, 0, 0);
            ap1 = __builtin_amdgcn_mfma_f32_16x16x32_bf16(af, W2F[(1 * 16 + kc) * 64 + lane], ap1, 0, 0, 0);
        }
#pragma unroll
        for (int rg = 0; rg < 4; ++rg) {
            pp[wave * 512 + 0 * 256 + lane * 4 + rg] = ap0[rg];
            pp[wave * 512 + 1 * 256 + lane * 4 + rg] = ap1[rg];
        }
    }
    __syncthreads();  // S6: partials ready
    // ---- reduce + MDN logsumexp (R6-verified shuffle pattern) ----
    float llm;
    {
        float pv = b2v;
#pragma unroll
        for (int w = 0; w < 8; ++w) pv += pp[ppofs + w * 512];
        const int half = lane & 32;
        float meanv = __shfl(pv, half + ((pc + 10) & 31), 64);
        float lsigv = __shfl(pv, half + ((pc + 20) & 31), 64);
        float e1, e2;
        if (pc < 10) {
            float ztar = z[(size_t)(b0 + mdn_mt) * DD + t0 + mdn_m];
            float invs = __expf(-lsigv);
            float dd = (ztar - meanv) * invs;
            e1 = -0.5f * dd * dd - lsigv - 0.91893853320467274f + pv;
            e2 = pv;
        } else { e1 = -FLT_MAX; e2 = -FLT_MAX; }
        float m1 = e1, m2 = e2;
#pragma unroll
        for (int off = 16; off > 0; off >>= 1) {
            m1 = fmaxf(m1, __shfl_xor(m1, off, 64));
            m2 = fmaxf(m2, __shfl_xor(m2, off, 64));
        }
        float s1 = (pc < 10) ? __expf(e1 - m1) : 0.0f;
        float s2 = (pc < 10) ? __expf(e2 - m2) : 0.0f;
#pragma unroll
        for (int off = 16; off > 0; off >>= 1) {
            s1 += __shfl_xor(s1, off, 64);
            s2 += __shfl_xor(s2, off, 64);
        }
        float ll = (m1 + __logf(s1)) - (m2 + __logf(s2));
        llm = ll * maskbuf[(size_t)(b0 + mdn_mt) * DD + t0 + mdn_m];
    }
    __syncthreads();  // S7: pp reads done before reuse
    if (pc == 0) pp[pr] = llm;
    __syncthreads();  // S8
    if (tid < 2) {
        float s = 0.0f;
#pragma unroll
        for (int j = 0; j < 16; ++j) s += pp[tid * 16 + j];
        atomicAdd(&out[b0 + tid], s);
    }
}

// ================= FALLBACK: R5-verified fused kernel (small workspace) =================
__global__ __launch_bounds__(1024, 4) void gru_mfma_r5(
    const float* __restrict__ z, const float* __restrict__ Wih,
    const float* __restrict__ bhh, const float* __restrict__ b1,
    const float* __restrict__ b2,
    const float* __restrict__ gi_const, const float* __restrict__ mlp_const,
    const float* __restrict__ maskbuf,
    const unsigned short* __restrict__ WhhP, const unsigned short* __restrict__ W0hP,
    const unsigned short* __restrict__ W1P, const unsigned short* __restrict__ W2P,
    float* __restrict__ out)
{
    __shared__ unsigned short h_bf[16 * 520];
    __shared__ unsigned short a_bf[16 * 520];
    __shared__ float pp[16 * 512];
    __shared__ float zbuf[113 * 16];
    __shared__ float mbuf[16 * 112];

    const int tid = threadIdx.x;
    const int wave = tid >> 6, lane = tid & 63;
    const int quad = lane >> 4, l16 = lane & 15;
    const int pr = tid >> 5, pc = tid & 31;
    const int rowBase = blockIdx.x * 16;

    for (int idx = tid; idx < 16 * 520; idx += 1024) h_bf[idx] = 0;
    for (int idx = tid; idx < 113 * 16; idx += 1024) {
        int tt = idx >> 4, r = idx & 15;
        zbuf[idx] = (tt == 0) ? -1.0f : z[(rowBase + r) * DD + tt - 1];
    }
    for (int idx = tid; idx < 16 * 112; idx += 1024) {
        int r = idx / DD, tt = idx - r * DD;
        mbuf[idx] = maskbuf[(rowBase + r) * DD + tt];
    }
    int hcol[2];
    float wz0[2], wz1[2], wz2[2], bh2r[2], b1c[2];
    float gic0[2][4], gic1[2][4], gic2[2][4], mlc[2][4];
    float h_own[2][4];
#pragma unroll
    for (int i = 0; i < 2; ++i) {
        int tile = wave + 16 * i;
        int hc = tile * 16 + l16;
        hcol[i] = hc;
        wz0[i] = Wih[hc]; wz1[i] = Wih[512 + hc]; wz2[i] = Wih[1024 + hc];
        float bh0 = bhh[hc], bh1 = bhh[512 + hc];
        bh2r[i] = bhh[1024 + hc];
        b1c[i] = b1[hc];
#pragma unroll
        for (int rg = 0; rg < 4; ++rg) {
            int m = quad * 4 + rg;
            const float* g = gi_const + (size_t)(rowBase + m) * G3;
            gic0[i][rg] = g[hc] + bh0;
            gic1[i][rg] = g[512 + hc] + bh1;
            gic2[i][rg] = g[1024 + hc];
            mlc[i][rg] = mlp_const[(size_t)(rowBase + m) * HIDD + hc];
            h_own[i][rg] = 0.0f;
        }
    }
    const float b2v = (pc < 30) ? b2[pc] : 0.0f;
    const int ppbase = (pc >> 4) * 256 + ((pr >> 2) * 16 + (pc & 15)) * 4 + (pr & 3);
    const short8* WhhF = (const short8*)WhhP;
    const short8* W0hF = (const short8*)W0hP;
    const short8* W1F  = (const short8*)W1P;
    const short8* W2F  = (const short8*)W2P;
    float llacc = 0.0f;
    __syncthreads();
    for (int t = 0; t < DD; ++t) {
        float4v accR[2], accU[2], accN[2];
#pragma unroll
        for (int i = 0; i < 2; ++i) {
            accR[i] = (float4v){gic0[i][0], gic0[i][1], gic0[i][2], gic0[i][3]};
            accU[i] = (float4v){gic1[i][0], gic1[i][1], gic1[i][2], gic1[i][3]};
            accN[i] = (float4v){0.f, 0.f, 0.f, 0.f};
        }
#pragma unroll 4
        for (int kc = 0; kc < 16; ++kc) {
            short8 af = *(const short8*)&h_bf[l16 * 520 + kc * 32 + quad * 8];
#pragma unroll
            for (int i = 0; i < 2; ++i) {
                int tile = wave + 16 * i;
                accR[i] = __builtin_amdgcn_mfma_f32_16x16x32_bf16(af, WhhF[(tile * 16 + kc) * 64 + lane], accR[i], 0, 0, 0);
                accU[i] = __builtin_amdgcn_mfma_f32_16x16x32_bf16(af, WhhF[((tile + 32) * 16 + kc) * 64 + lane], accU[i], 0, 0, 0);
                accN[i] = __builtin_amdgcn_mfma_f32_16x16x32_bf16(af, WhhF[((tile + 64) * 16 + kc) * 64 + lane], accN[i], 0, 0, 0);
            }
        }
        __syncthreads();
#pragma unroll
        for (int i = 0; i < 2; ++i) {
#pragma unroll
            for (int rg = 0; rg < 4; ++rg) {
                int m = quad * 4 + rg;
                float zt = zbuf[t * 16 + m];
                float r = 1.0f / (1.0f + __expf(-(accR[i][rg] + zt * wz0[i])));
                float u = 1.0f / (1.0f + __expf(-(accU[i][rg] + zt * wz1[i])));
                float xn = gic2[i][rg] + zt * wz2[i] + r * (accN[i][rg] + bh2r[i]);
                float n = 1.0f - 2.0f / (__expf(2.0f * xn) + 1.0f);
                float h2 = (1.0f - u) * n + u * h_own[i][rg];
                h_own[i][rg] = h2;
                h_bf[m * 520 + hcol[i]] = f2bf(h2);
            }
        }
        __syncthreads();
        float4v acc1[2];
#pragma unroll
        for (int i = 0; i < 2; ++i) acc1[i] = (float4v){mlc[i][0], mlc[i][1], mlc[i][2], mlc[i][3]};
#pragma unroll 4
        for (int kc = 0; kc < 16; ++kc) {
            short8 af = *(const short8*)&h_bf[l16 * 520 + kc * 32 + quad * 8];
#pragma unroll
            for (int i = 0; i < 2; ++i)
                acc1[i] = __builtin_amdgcn_mfma_f32_16x16x32_bf16(af, W0hF[((wave + 16 * i) * 16 + kc) * 64 + lane], acc1[i], 0, 0, 0);
        }
#pragma unroll
        for (int i = 0; i < 2; ++i)
#pragma unroll
            for (int rg = 0; rg < 4; ++rg) {
                int m = quad * 4 + rg;
                float x = acc1[i][rg];
                a_bf[m * 520 + hcol[i]] = f2bf(1.0f - 2.0f / (__expf(2.0f * x) + 1.0f));
            }
        __syncthreads();
        float4v acc2[2];
#pragma unroll
        for (int i = 0; i < 2; ++i) acc2[i] = (float4v){b1c[i], b1c[i], b1c[i], b1c[i]};
#pragma unroll 4
        for (int kc = 0; kc < 16; ++kc) {
            short8 af = *(const short8*)&a_bf[l16 * 520 + kc * 32 + quad * 8];
#pragma unroll
            for (int i = 0; i < 2; ++i)
                acc2[i] = __builtin_amdgcn_mfma_f32_16x16x32_bf16(af, W1F[((wave + 16 * i) * 16 + kc) * 64 + lane], acc2[i], 0, 0, 0);
        }
        __syncthreads();
#pragma unroll
        for (int i = 0; i < 2; ++i)
#pragma unroll
            for (int rg = 0; rg < 4; ++rg) {
                int m = quad * 4 + rg;
                float x = acc2[i][rg];
                a_bf[m * 520 + hcol[i]] = f2bf(1.0f - 2.0f / (__expf(2.0f * x) + 1.0f));
            }
        __syncthreads();
        {
            int kc = wave;
            short8 af = *(const short8*)&a_bf[l16 * 520 + kc * 32 + quad * 8];
            float4v ap0 = (float4v){0.f, 0.f, 0.f, 0.f}, ap1 = (float4v){0.f, 0.f, 0.f, 0.f};
            ap0 = __builtin_amdgcn_mfma_f32_16x16x32_bf16(af, W2F[(0 * 16 + kc) * 64 + lane], ap0, 0, 0, 0);
            ap1 = __builtin_amdgcn_mfma_f32_16x16x32_bf16(af, W2F[(1 * 16 + kc) * 64 + lane], ap1, 0, 0, 0);
#pragma unroll
            for (int rg = 0; rg < 4; ++rg) {
                pp[wave * 512 + 0 * 256 + lane * 4 + rg] = ap0[rg];
                pp[wave * 512 + 1 * 256 + lane * 4 + rg] = ap1[rg];
            }
        }
        __syncthreads();
        if (wave < 8) {
            float pv = b2v;
#pragma unroll
            for (int w = 0; w < 16; ++w) pv += pp[w * 512 + ppbase];
            const int half = lane & 32;
            float meanv = __shfl(pv, half + ((pc + 10) & 31), 64);
            float lsigv = __shfl(pv, half + ((pc + 20) & 31), 64);
            float e1, e2;
            if (pc < 10) {
                float ztar = zbuf[(t + 1) * 16 + pr];
                float invs = __expf(-lsigv);
                float dd = (ztar - meanv) * invs;
                e1 = -0.5f * dd * dd - lsigv - 0.91893853320467274f + pv;
                e2 = pv;
            } else { e1 = -FLT_MAX; e2 = -FLT_MAX; }
            float m1 = e1, m2 = e2;
#pragma unroll
            for (int off = 16; off > 0; off >>= 1) {
                m1 = fmaxf(m1, __shfl_xor(m1, off, 64));
                m2 = fmaxf(m2, __shfl_xor(m2, off, 64));
            }
            float s1 = (pc < 10) ? __expf(e1 - m1) : 0.0f;
            float s2 = (pc < 10) ? __expf(e2 - m2) : 0.0f;
#pragma unroll
            for (int off = 16; off > 0; off >>= 1) {
                s1 += __shfl_xor(s1, off, 64);
                s2 += __shfl_xor(s2, off, 64);
            }
            float ll = (m1 + __logf(s1)) - (m2 + __logf(s2));
            llacc += ll * mbuf[pr * 112 + t];
        }
    }
    if (wave < 8 && pc == 0) out[rowBase + pr] = llacc;
}

extern "C" void kernel_launch(void* const* d_in, const int* in_sizes, int n_in,
                              void* d_out, int out_size, void* d_ws, size_t ws_size,
                              hipStream_t stream) {
    const float* z   = (const float*)d_in[0];
    const float* c   = (const float*)d_in[1];
    const float* b   = (const float*)d_in[2];
    const float* m   = (const float*)d_in[3];
    const float* Wih = (const float*)d_in[4];
    const float* Whh = (const float*)d_in[5];
    const float* bih = (const float*)d_in[6];
    const float* bhh = (const float*)d_in[7];
    const float* W0  = (const float*)d_in[8];
    const float* b0  = (const float*)d_in[9];
    const float* W1  = (const float*)d_in[10];
    const float* b1  = (const float*)d_in[11];
    const float* W2  = (const float*)d_in[12];
    const float* b2  = (const float*)d_in[13];
    float* out = (float*)d_out;

    float* ws        = (float*)d_ws;
    float* constbuf  = ws;                                   // B*536
    float* gi_region = constbuf + (size_t)BN * CW;           // B*1536 (gicP or row-major)
    float* mlp_const = gi_region + (size_t)BN * G3;          // B*512
    float* maskbuf   = mlp_const + (size_t)BN * HIDD;        // B*112
    unsigned short* WhhP = (unsigned short*)(maskbuf + (size_t)BN * DD);
    unsigned short* W0hP = WhhP + (size_t)96 * 16 * 512;
    unsigned short* W1P  = W0hP + (size_t)32 * 16 * 512;
    unsigned short* W2P  = W1P  + (size_t)32 * 16 * 512;
    unsigned short* h2g  = W2P + (size_t)2 * 16 * 512;       // B*112*512 bf16 (split path)

    const size_t need = (size_t)(constbuf ? 0 : 0)
        + ((size_t)BN * (CW + G3 + HIDD + DD)) * 4
        + ((size_t)(96 + 32 + 32 + 2) * 16 * 512) * 2
        + (size_t)BN * DD * 512 * 2;

    build_const<<<(BN * CW + 255) / 256, 256, 0, stream>>>(c, b, m, constbuf);
    dim3 g2(BN / 64, HIDD / 64);
    gemm_bias<<<g2, 256, 0, stream>>>(constbuf, W0 + (size_t)HH * HIDD, b0, mlp_const, HIDD);
    sort_mask<<<BN, 128, 0, stream>>>(b, m, maskbuf);
    pack_w<<<96 * 16, 64, 0, stream>>>(Whh, WhhP, 16, G3, G3);
    pack_w<<<32 * 16, 64, 0, stream>>>(W0,  W0hP, 16, HIDD, HIDD);
    pack_w<<<32 * 16, 64, 0, stream>>>(W1,  W1P,  16, HIDD, HIDD);
    pack_w<<<2 * 16, 64, 0, stream>>>(W2,  W2P,  16, 30, 30);

    dim3 g1(BN / 64, G3 / 64);
    if (ws_size >= need) {
        // split path: recurrence (M=32) then batched head
        gemm_gicP<<<g1, 256, 0, stream>>>(constbuf, Wih + G3, bih, bhh, gi_region);
        hipMemsetAsync(d_out, 0, (size_t)out_size * sizeof(float), stream);
        gru_rec<<<BN / 32, 1024, 0, stream>>>(z, Wih, bhh, gi_region, WhhP, h2g);
        head_mdn<<<(BN / 2) * (DD / 16), 1024, 0, stream>>>(z, b1, b2, mlp_const,
                                                            maskbuf, h2g, W0hP, W1P, W2P, out);
    } else {
        // fallback: R5-verified fused kernel
        gemm_bias<<<g1, 256, 0, stream>>>(constbuf, Wih + G3, bih, gi_region, G3);
        gru_mfma_r5<<<BN / 16, 1024, 0, stream>>>(z, Wih, bhh, b1, b2, gi_region,
                                                  mlp_const, maskbuf, WhhP, W0hP, W1P, W2P, out);
    }
}

// Round 8
// 2971.418 us; speedup vs baseline: 1.5246x; 1.0608x over previous
//
#include <hip/hip_runtime.h>
#include <hip/hip_bf16.h>
#include <float.h>
#include <math.h>

#define BN   4096
#define DD   112
#define HH   512
#define G3   1536
#define CW   536
#define HIDD 512

typedef __attribute__((ext_vector_type(8))) short short8;
typedef __attribute__((ext_vector_type(4))) float float4v;

__device__ __forceinline__ unsigned short f2bf(float x) {
    __hip_bfloat16 h = __float2bfloat16(x);
    return *(unsigned short*)&h;
}

// ---------------- materialize const = [c | b | m]  (B x 536) ----------------
__global__ void build_const(const float* __restrict__ c, const float* __restrict__ b,
                            const float* __restrict__ m, float* __restrict__ out) {
    int idx = blockIdx.x * blockDim.x + threadIdx.x;
    if (idx >= BN * CW) return;
    int row = idx / CW, col = idx - row * CW;
    float v;
    if (col < 312)      v = c[row * 312 + col];
    else if (col < 424) v = b[row * 112 + (col - 312)];
    else                v = m[row * 112 + (col - 424)];
    out[idx] = v;
}

__global__ void zero_f32(float* __restrict__ p, int n) {
    int i = blockIdx.x * blockDim.x + threadIdx.x;
    if (i < n) p[i] = 0.0f;
}

// ---------------- generic fp32 GEMM + bias (row-major out) ----------------
__global__ __launch_bounds__(256) void gemm_bias(const float* __restrict__ A,
        const float* __restrict__ W, const float* __restrict__ bias,
        float* __restrict__ C, int N) {
    __shared__ float As[8][64];
    __shared__ float Ws[8][64];
    const int tid = threadIdx.x;
    const int tx = tid & 15, ty = tid >> 4;
    const int rowBase = blockIdx.x * 64, colBase = blockIdx.y * 64;
    float acc[4][4] = {};
    for (int kb = 0; kb < CW; kb += 8) {
        int l = tid * 2;
        {
            int i = l >> 3, j = l & 7;
            As[j][i] = A[(rowBase + i) * CW + kb + j];
            int i2 = (l + 1) >> 3, j2 = (l + 1) & 7;
            As[j2][i2] = A[(rowBase + i2) * CW + kb + j2];
        }
        {
            int j = l >> 6, n = l & 63;
            Ws[j][n] = W[(kb + j) * N + colBase + n];
            int j2 = (l + 1) >> 6, n2 = (l + 1) & 63;
            Ws[j2][n2] = W[(kb + j2) * N + colBase + n2];
        }
        __syncthreads();
#pragma unroll
        for (int k = 0; k < 8; ++k) {
            float av[4], wv[4];
#pragma unroll
            for (int i = 0; i < 4; ++i) av[i] = As[k][ty * 4 + i];
#pragma unroll
            for (int j = 0; j < 4; ++j) wv[j] = Ws[k][tx * 4 + j];
#pragma unroll
            for (int i = 0; i < 4; ++i)
#pragma unroll
                for (int j = 0; j < 4; ++j) acc[i][j] += av[i] * wv[j];
        }
        __syncthreads();
    }
#pragma unroll
    for (int i = 0; i < 4; ++i) {
        int r = rowBase + ty * 4 + i;
#pragma unroll
        for (int j = 0; j < 4; ++j) {
            int cc = colBase + tx * 4 + j;
            C[r * N + cc] = acc[i][j] + bias[cc];
        }
    }
}

// ---------------- mask = descending sort of m*(1-b) per row ----------------
__global__ void sort_mask(const float* __restrict__ b, const float* __restrict__ m,
                          float* __restrict__ maskbuf) {
    __shared__ float s[128];
    const int row = blockIdx.x, t = threadIdx.x;
    float v = -FLT_MAX;
    if (t < DD) v = m[row * DD + t] * (1.0f - b[row * DD + t]);
    s[t] = v;
    __syncthreads();
    for (int k = 2; k <= 128; k <<= 1) {
        for (int j = k >> 1; j > 0; j >>= 1) {
            int ixj = t ^ j;
            if (ixj > t) {
                bool up = ((t & k) == 0);
                float a = s[t], bb = s[ixj];
                if ((a > bb) == up) { s[t] = bb; s[ixj] = a; }
            }
            __syncthreads();
        }
    }
    if (t < DD) maskbuf[row * DD + t] = s[127 - t];
}

// ---------------- pack weight [K][N] -> MFMA B-fragments ----------------
__global__ void pack_w(const float* __restrict__ src, unsigned short* __restrict__ dst,
                       int kchunks, int ldn, int ncols) {
    int bid = blockIdx.x;
    int nt = bid / kchunks, kc = bid - nt * kchunks;
    int lane = threadIdx.x;
    int quad = lane >> 4, l16 = lane & 15;
    int n = nt * 16 + l16;
    unsigned short v[8];
#pragma unroll
    for (int j = 0; j < 8; ++j) {
        int k = kc * 32 + quad * 8 + j;
        float f = (n < ncols) ? src[(size_t)k * ldn + n] : 0.0f;
        v[j] = f2bf(f);
    }
    unsigned short* p = dst + ((size_t)bid * 64 + lane) * 8;
#pragma unroll
    for (int j = 0; j < 8; ++j) p[j] = v[j];
}

// ================= KERNEL A: GRU recurrence chunk (M=16, 256 blocks, 16 waves) =================
// Runs steps [t0, t0+tlen); h state persisted in hstate (fp32); h2 written bf16
// to slab h2g[(t-t0)*BN + row][col].
__global__ __launch_bounds__(1024, 4) void gru_rec_chunk(
    const float* __restrict__ z, const float* __restrict__ Wih,
    const float* __restrict__ bhh, const float* __restrict__ gi_const,
    const unsigned short* __restrict__ WhhP,
    float* __restrict__ hstate, unsigned short* __restrict__ h2g,
    int t0, int tlen)
{
    __shared__ unsigned short h_bf[16 * 520];
    __shared__ float zbuf[113 * 16];

    const int tid = threadIdx.x;
    const int wave = tid >> 6, lane = tid & 63;
    const int quad = lane >> 4, l16 = lane & 15;
    const int rowBase = blockIdx.x * 16;

    for (int idx = tid; idx < 113 * 16; idx += 1024) {
        int tt = idx >> 4, r = idx & 15;
        zbuf[idx] = (tt == 0) ? -1.0f : z[(rowBase + r) * DD + tt - 1];
    }

    int hcol[2];
    float wz0[2], wz1[2], wz2[2], bh2r[2];
    float gic0[2][4], gic1[2][4], gic2[2][4];
    float h_own[2][4];
#pragma unroll
    for (int i = 0; i < 2; ++i) {
        int tile = wave + 16 * i;
        int hc = tile * 16 + l16;
        hcol[i] = hc;
        wz0[i] = Wih[hc]; wz1[i] = Wih[512 + hc]; wz2[i] = Wih[1024 + hc];
        float bh0 = bhh[hc], bh1 = bhh[512 + hc];
        bh2r[i] = bhh[1024 + hc];
#pragma unroll
        for (int rg = 0; rg < 4; ++rg) {
            int m = quad * 4 + rg;
            const float* g = gi_const + (size_t)(rowBase + m) * G3;
            gic0[i][rg] = g[hc] + bh0;
            gic1[i][rg] = g[512 + hc] + bh1;
            gic2[i][rg] = g[1024 + hc];
            float hv = hstate[(size_t)(rowBase + m) * HH + hc];
            h_own[i][rg] = hv;
            h_bf[m * 520 + hc] = f2bf(hv);
        }
    }
    const short8* WhhF = (const short8*)WhhP;
    __syncthreads();

    for (int tt = 0; tt < tlen; ++tt) {
        const int t = t0 + tt;
        float4v accR[2], accU[2], accN[2];
#pragma unroll
        for (int i = 0; i < 2; ++i) {
            accR[i] = (float4v){gic0[i][0], gic0[i][1], gic0[i][2], gic0[i][3]};
            accU[i] = (float4v){gic1[i][0], gic1[i][1], gic1[i][2], gic1[i][3]};
            accN[i] = (float4v){0.f, 0.f, 0.f, 0.f};
        }
#pragma unroll 4
        for (int kc = 0; kc < 16; ++kc) {
            short8 af = *(const short8*)&h_bf[l16 * 520 + kc * 32 + quad * 8];
#pragma unroll
            for (int i = 0; i < 2; ++i) {
                int tile = wave + 16 * i;
                accR[i] = __builtin_amdgcn_mfma_f32_16x16x32_bf16(af, WhhF[(tile * 16 + kc) * 64 + lane], accR[i], 0, 0, 0);
                accU[i] = __builtin_amdgcn_mfma_f32_16x16x32_bf16(af, WhhF[((tile + 32) * 16 + kc) * 64 + lane], accU[i], 0, 0, 0);
                accN[i] = __builtin_amdgcn_mfma_f32_16x16x32_bf16(af, WhhF[((tile + 64) * 16 + kc) * 64 + lane], accN[i], 0, 0, 0);
            }
        }
        __syncthreads();  // S1: all A-frag reads done
#pragma unroll
        for (int i = 0; i < 2; ++i) {
#pragma unroll
            for (int rg = 0; rg < 4; ++rg) {
                int m = quad * 4 + rg;
                float zt = zbuf[t * 16 + m];
                float r = 1.0f / (1.0f + __expf(-(accR[i][rg] + zt * wz0[i])));
                float u = 1.0f / (1.0f + __expf(-(accU[i][rg] + zt * wz1[i])));
                float xn = gic2[i][rg] + zt * wz2[i] + r * (accN[i][rg] + bh2r[i]);
                float n = 1.0f - 2.0f / (__expf(2.0f * xn) + 1.0f);
                float h2 = (1.0f - u) * n + u * h_own[i][rg];
                h_own[i][rg] = h2;
                h_bf[m * 520 + hcol[i]] = f2bf(h2);
            }
        }
        __syncthreads();  // S2: mirror complete
        // slab store: wave w -> row w; thread -> 8 contiguous bf16 (16B)
        {
            int col = (lane) * 8;
            uint4 v = *(const uint4*)&h_bf[wave * 520 + col];
            *(uint4*)&h2g[((size_t)tt * BN + rowBase + wave) * 512 + col] = v;
        }
        // h_bf rewritten only after next S1 -> store reads are safe
    }
    // persist h state for next chunk
#pragma unroll
    for (int i = 0; i < 2; ++i)
#pragma unroll
        for (int rg = 0; rg < 4; ++rg)
            hstate[(size_t)(rowBase + quad * 4 + rg) * HH + hcol[i]] = h_own[i][rg];
}

// ================= KERNEL B: MLP head + MDN over slab rows =================
// grid (BN/2, tlen/16); block = 2 batch-rows x 16 timesteps (M=32), 16 waves.
__global__ __launch_bounds__(1024, 4) void head_mdn(
    const float* __restrict__ z, const float* __restrict__ b1,
    const float* __restrict__ b2, const float* __restrict__ mlp_const,
    const float* __restrict__ maskbuf, const unsigned short* __restrict__ h2g,
    const unsigned short* __restrict__ W0hP, const unsigned short* __restrict__ W1P,
    const unsigned short* __restrict__ W2P, float* __restrict__ out, int t0)
{
    __shared__ unsigned short h_bf[32 * 520];
    __shared__ unsigned short a_bf[32 * 520];
    __shared__ float pp[16 * 512];

    const int tid = threadIdx.x;
    const int wave = tid >> 6, lane = tid & 63;
    const int quad = lane >> 4, l16 = lane & 15;
    const int pr = tid >> 5, pc = tid & 31;
    const int b0 = blockIdx.x * 2;
    const int tg = blockIdx.y;

    // stage h2 tile: row r = mt*16+toff <-> (b0+mt, trel=tg*16+toff)
    {
        int flat = tid * 16;
        int r = flat >> 9, col = flat & 511;
        int bb = b0 + (r >> 4), trel = tg * 16 + (r & 15);
        uint4 v0 = ((const uint4*)&h2g[((size_t)trel * BN + bb) * 512 + col])[0];
        uint4 v1 = ((const uint4*)&h2g[((size_t)trel * BN + bb) * 512 + col])[1];
        uint4* dst = (uint4*)&h_bf[r * 520 + col];
        dst[0] = v0; dst[1] = v1;
    }
    int hcol[2];
    float b1c[2], mlc[2][2];
#pragma unroll
    for (int i = 0; i < 2; ++i) {
        int hc = (wave + 16 * i) * 16 + l16;
        hcol[i] = hc;
        b1c[i] = b1[hc];
#pragma unroll
        for (int mt = 0; mt < 2; ++mt) mlc[i][mt] = mlp_const[(size_t)(b0 + mt) * HIDD + hc];
    }
    const float b2v = (pc < 30) ? b2[pc] : 0.0f;
    const int mdn_mt = pr >> 4, mdn_m = pr & 15;   // batch-sub, t-offset
    const int ppofs = (mdn_mt * 8) * 512 + (pc >> 4) * 256
                      + ((mdn_m >> 2) * 16 + (pc & 15)) * 4 + (mdn_m & 3);

    const short8* W0hF = (const short8*)W0hP;
    const short8* W1F  = (const short8*)W1P;
    const short8* W2F  = (const short8*)W2P;
    __syncthreads();  // S0: h tile staged

    // ---- a1 = tanh(h2 @ W0h + mlc[b]) ----
    float4v acc1[2][2];
#pragma unroll
    for (int i = 0; i < 2; ++i)
#pragma unroll
        for (int mt = 0; mt < 2; ++mt)
            acc1[i][mt] = (float4v){mlc[i][mt], mlc[i][mt], mlc[i][mt], mlc[i][mt]};
#pragma unroll 4
    for (int kc = 0; kc < 16; ++kc) {
        short8 af0 = *(const short8*)&h_bf[l16 * 520 + kc * 32 + quad * 8];
        short8 af1 = *(const short8*)&h_bf[(16 + l16) * 520 + kc * 32 + quad * 8];
#pragma unroll
        for (int i = 0; i < 2; ++i) {
            short8 bf = W0hF[((wave + 16 * i) * 16 + kc) * 64 + lane];
            acc1[i][0] = __builtin_amdgcn_mfma_f32_16x16x32_bf16(af0, bf, acc1[i][0], 0, 0, 0);
            acc1[i][1] = __builtin_amdgcn_mfma_f32_16x16x32_bf16(af1, bf, acc1[i][1], 0, 0, 0);
        }
    }
#pragma unroll
    for (int i = 0; i < 2; ++i)
#pragma unroll
        for (int mt = 0; mt < 2; ++mt)
#pragma unroll
            for (int rg = 0; rg < 4; ++rg) {
                int m = mt * 16 + quad * 4 + rg;
                float x = acc1[i][mt][rg];
                a_bf[m * 520 + hcol[i]] = f2bf(1.0f - 2.0f / (__expf(2.0f * x) + 1.0f));
            }
    __syncthreads();  // S3: a1 ready
    // ---- a2 = tanh(a1 @ W1 + b1) ----
    float4v acc2[2][2];
#pragma unroll
    for (int i = 0; i < 2; ++i)
#pragma unroll
        for (int mt = 0; mt < 2; ++mt)
            acc2[i][mt] = (float4v){b1c[i], b1c[i], b1c[i], b1c[i]};
#pragma unroll 4
    for (int kc = 0; kc < 16; ++kc) {
        short8 af0 = *(const short8*)&a_bf[l16 * 520 + kc * 32 + quad * 8];
        short8 af1 = *(const short8*)&a_bf[(16 + l16) * 520 + kc * 32 + quad * 8];
#pragma unroll
        for (int i = 0; i < 2; ++i) {
            short8 bf = W1F[((wave + 16 * i) * 16 + kc) * 64 + lane];
            acc2[i][0] = __builtin_amdgcn_mfma_f32_16x16x32_bf16(af0, bf, acc2[i][0], 0, 0, 0);
            acc2[i][1] = __builtin_amdgcn_mfma_f32_16x16x32_bf16(af1, bf, acc2[i][1], 0, 0, 0);
        }
    }
    __syncthreads();  // S4: all reads of a1 done
#pragma unroll
    for (int i = 0; i < 2; ++i)
#pragma unroll
        for (int mt = 0; mt < 2; ++mt)
#pragma unroll
            for (int rg = 0; rg < 4; ++rg) {
                int m = mt * 16 + quad * 4 + rg;
                float x = acc2[i][mt][rg];
                a_bf[m * 520 + hcol[i]] = f2bf(1.0f - 2.0f / (__expf(2.0f * x) + 1.0f));
            }
    __syncthreads();  // S5: a2 ready
    // ---- p = a2 @ W2 + b2 : wave -> mt = w>>3, kc pair (w&7)*2..+1 ----
    {
        const int mtw = wave >> 3;
        float4v ap0 = (float4v){0.f, 0.f, 0.f, 0.f}, ap1 = (float4v){0.f, 0.f, 0.f, 0.f};
#pragma unroll
        for (int kk = 0; kk < 2; ++kk) {
            int kc = (wave & 7) * 2 + kk;
            short8 af = *(const short8*)&a_bf[(mtw * 16 + l16) * 520 + kc * 32 + quad * 8];
            ap0 = __builtin_amdgcn_mfma_f32_16x16x32_bf16(af, W2F[(0 * 16 + kc) * 64 + lane], ap0, 0, 0, 0);
            ap1 = __builtin_amdgcn_mfma_f32_16x16x32_bf16(af, W2F[(1 * 16 + kc) * 64 + lane], ap1, 0, 0, 0);
        }
#pragma unroll
        for (int rg = 0; rg < 4; ++rg) {
            pp[wave * 512 + 0 * 256 + lane * 4 + rg] = ap0[rg];
            pp[wave * 512 + 1 * 256 + lane * 4 + rg] = ap1[rg];
        }
    }
    __syncthreads();  // S6: partials ready
    // ---- reduce + MDN logsumexp ----
    float llm;
    {
        float pv = b2v;
#pragma unroll
        for (int w = 0; w < 8; ++w) pv += pp[ppofs + w * 512];
        const int half = lane & 32;
        float meanv = __shfl(pv, half + ((pc + 10) & 31), 64);
        float lsigv = __shfl(pv, half + ((pc + 20) & 31), 64);
        float e1, e2;
        if (pc < 10) {
            float ztar = z[(size_t)(b0 + mdn_mt) * DD + t0 + tg * 16 + mdn_m];
            float invs = __expf(-lsigv);
            float dd = (ztar - meanv) * invs;
            e1 = -0.5f * dd * dd - lsigv - 0.91893853320467274f + pv;
            e2 = pv;
        } else { e1 = -FLT_MAX; e2 = -FLT_MAX; }
        float m1 = e1, m2 = e2;
#pragma unroll
        for (int off = 16; off > 0; off >>= 1) {
            m1 = fmaxf(m1, __shfl_xor(m1, off, 64));
            m2 = fmaxf(m2, __shfl_xor(m2, off, 64));
        }
        float s1 = (pc < 10) ? __expf(e1 - m1) : 0.0f;
        float s2 = (pc < 10) ? __expf(e2 - m2) : 0.0f;
#pragma unroll
        for (int off = 16; off > 0; off >>= 1) {
            s1 += __shfl_xor(s1, off, 64);
            s2 += __shfl_xor(s2, off, 64);
        }
        float ll = (m1 + __logf(s1)) - (m2 + __logf(s2));
        llm = ll * maskbuf[(size_t)(b0 + mdn_mt) * DD + t0 + tg * 16 + mdn_m];
    }
    __syncthreads();  // S7: pp reads done before reuse
    if (pc == 0) pp[pr] = llm;
    __syncthreads();  // S8
    if (tid < 2) {
        float s = 0.0f;
#pragma unroll
        for (int j = 0; j < 16; ++j) s += pp[tid * 16 + j];
        atomicAdd(&out[b0 + tid], s);
    }
}

// ================= FALLBACK: R5-verified fused kernel (small workspace) =================
__global__ __launch_bounds__(1024, 4) void gru_mfma_r5(
    const float* __restrict__ z, const float* __restrict__ Wih,
    const float* __restrict__ bhh, const float* __restrict__ b1,
    const float* __restrict__ b2,
    const float* __restrict__ gi_const, const float* __restrict__ mlp_const,
    const float* __restrict__ maskbuf,
    const unsigned short* __restrict__ WhhP, const unsigned short* __restrict__ W0hP,
    const unsigned short* __restrict__ W1P, const unsigned short* __restrict__ W2P,
    float* __restrict__ out)
{
    __shared__ unsigned short h_bf[16 * 520];
    __shared__ unsigned short a_bf[16 * 520];
    __shared__ float pp[16 * 512];
    __shared__ float zbuf[113 * 16];
    __shared__ float mbuf[16 * 112];

    const int tid = threadIdx.x;
    const int wave = tid >> 6, lane = tid & 63;
    const int quad = lane >> 4, l16 = lane & 15;
    const int pr = tid >> 5, pc = tid & 31;
    const int rowBase = blockIdx.x * 16;

    for (int idx = tid; idx < 16 * 520; idx += 1024) h_bf[idx] = 0;
    for (int idx = tid; idx < 113 * 16; idx += 1024) {
        int tt = idx >> 4, r = idx & 15;
        zbuf[idx] = (tt == 0) ? -1.0f : z[(rowBase + r) * DD + tt - 1];
    }
    for (int idx = tid; idx < 16 * 112; idx += 1024) {
        int r = idx / DD, tt = idx - r * DD;
        mbuf[idx] = maskbuf[(rowBase + r) * DD + tt];
    }
    int hcol[2];
    float wz0[2], wz1[2], wz2[2], bh2r[2], b1c[2];
    float gic0[2][4], gic1[2][4], gic2[2][4], mlc[2][4];
    float h_own[2][4];
#pragma unroll
    for (int i = 0; i < 2; ++i) {
        int tile = wave + 16 * i;
        int hc = tile * 16 + l16;
        hcol[i] = hc;
        wz0[i] = Wih[hc]; wz1[i] = Wih[512 + hc]; wz2[i] = Wih[1024 + hc];
        float bh0 = bhh[hc], bh1 = bhh[512 + hc];
        bh2r[i] = bhh[1024 + hc];
        b1c[i] = b1[hc];
#pragma unroll
        for (int rg = 0; rg < 4; ++rg) {
            int m = quad * 4 + rg;
            const float* g = gi_const + (size_t)(rowBase + m) * G3;
            gic0[i][rg] = g[hc] + bh0;
            gic1[i][rg] = g[512 + hc] + bh1;
            gic2[i][rg] = g[1024 + hc];
            mlc[i][rg] = mlp_const[(size_t)(rowBase + m) * HIDD + hc];
            h_own[i][rg] = 0.0f;
        }
    }
    const float b2v = (pc < 30) ? b2[pc] : 0.0f;
    const int ppbase = (pc >> 4) * 256 + ((pr >> 2) * 16 + (pc & 15)) * 4 + (pr & 3);
    const short8* WhhF = (const short8*)WhhP;
    const short8* W0hF = (const short8*)W0hP;
    const short8* W1F  = (const short8*)W1P;
    const short8* W2F  = (const short8*)W2P;
    float llacc = 0.0f;
    __syncthreads();
    for (int t = 0; t < DD; ++t) {
        float4v accR[2], accU[2], accN[2];
#pragma unroll
        for (int i = 0; i < 2; ++i) {
            accR[i] = (float4v){gic0[i][0], gic0[i][1], gic0[i][2], gic0[i][3]};
            accU[i] = (float4v){gic1[i][0], gic1[i][1], gic1[i][2], gic1[i][3]};
            accN[i] = (float4v){0.f, 0.f, 0.f, 0.f};
        }
#pragma unroll 4
        for (int kc = 0; kc < 16; ++kc) {
            short8 af = *(const short8*)&h_bf[l16 * 520 + kc * 32 + quad * 8];
#pragma unroll
            for (int i = 0; i < 2; ++i) {
                int tile = wave + 16 * i;
                accR[i] = __builtin_amdgcn_mfma_f32_16x16x32_bf16(af, WhhF[(tile * 16 + kc) * 64 + lane], accR[i], 0, 0, 0);
                accU[i] = __builtin_amdgcn_mfma_f32_16x16x32_bf16(af, WhhF[((tile + 32) * 16 + kc) * 64 + lane], accU[i], 0, 0, 0);
                accN[i] = __builtin_amdgcn_mfma_f32_16x16x32_bf16(af, WhhF[((tile + 64) * 16 + kc) * 64 + lane], accN[i], 0, 0, 0);
            }
        }
        __syncthreads();
#pragma unroll
        for (int i = 0; i < 2; ++i) {
#pragma unroll
            for (int rg = 0; rg < 4; ++rg) {
                int m = quad * 4 + rg;
                float zt = zbuf[t * 16 + m];
                float r = 1.0f / (1.0f + __expf(-(accR[i][rg] + zt * wz0[i])));
                float u = 1.0f / (1.0f + __expf(-(accU[i][rg] + zt * wz1[i])));
                float xn = gic2[i][rg] + zt * wz2[i] + r * (accN[i][rg] + bh2r[i]);
                float n = 1.0f - 2.0f / (__expf(2.0f * xn) + 1.0f);
                float h2 = (1.0f - u) * n + u * h_own[i][rg];
                h_own[i][rg] = h2;
                h_bf[m * 520 + hcol[i]] = f2bf(h2);
            }
        }
        __syncthreads();
        float4v acc1[2];
#pragma unroll
        for (int i = 0; i < 2; ++i) acc1[i] = (float4v){mlc[i][0], mlc[i][1], mlc[i][2], mlc[i][3]};
#pragma unroll 4
        for (int kc = 0; kc < 16; ++kc) {
            short8 af = *(const short8*)&h_bf[l16 * 520 + kc * 32 + quad * 8];
#pragma unroll
            for (int i = 0; i < 2; ++i)
                acc1[i] = __builtin_amdgcn_mfma_f32_16x16x32_bf16(af, W0hF[((wave + 16 * i) * 16 + kc) * 64 + lane], acc1[i], 0, 0, 0);
        }
#pragma unroll
        for (int i = 0; i < 2; ++i)
#pragma unroll
            for (int rg = 0; rg < 4; ++rg) {
                int m = quad * 4 + rg;
                float x = acc1[i][rg];
                a_bf[m * 520 + hcol[i]] = f2bf(1.0f - 2.0f / (__expf(2.0f * x) + 1.0f));
            }
        __syncthreads();
        float4v acc2[2];
#pragma unroll
        for (int i = 0; i < 2; ++i) acc2[i] = (float4v){b1c[i], b1c[i], b1c[i], b1c[i]};
#pragma unroll 4
        for (int kc = 0; kc < 16; ++kc) {
            short8 af = *(const short8*)&a_bf[l16 * 520 + kc * 32 + quad * 8];
#pragma unroll
            for (int i = 0; i < 2; ++i)
                acc2[i] = __builtin_amdgcn_mfma_f32_16x16x32_bf16(af, W1F[((wave + 16 * i) * 16 + kc) * 64 + lane], acc2[i], 0, 0, 0);
        }
        __syncthreads();
#pragma unroll
        for (int i = 0; i < 2; ++i)
#pragma unroll
            for (int rg = 0; rg < 4; ++rg) {
                int m = quad * 4 + rg;
                float x = acc2[i][rg];
                a_bf[m * 520 + hcol[i]] = f2bf(1.0f - 2.0f / (__expf(2.0f * x) + 1.0f));
            }
        __syncthreads();
        {
            int kc = wave;
            short8 af = *(const short8*)&a_bf[l16 * 520 + kc * 32 + quad * 8];
            float4v ap0 = (float4v){0.f, 0.f, 0.f, 0.f}, ap1 = (float4v){0.f, 0.f, 0.f, 0.f};
            ap0 = __builtin_amdgcn_mfma_f32_16x16x32_bf16(af, W2F[(0 * 16 + kc) * 64 + lane], ap0, 0, 0, 0);
            ap1 = __builtin_amdgcn_mfma_f32_16x16x32_bf16(af, W2F[(1 * 16 + kc) * 64 + lane], ap1, 0, 0, 0);
#pragma unroll
            for (int rg = 0; rg < 4; ++rg) {
                pp[wave * 512 + 0 * 256 + lane * 4 + rg] = ap0[rg];
                pp[wave * 512 + 1 * 256 + lane * 4 + rg] = ap1[rg];
            }
        }
        __syncthreads();
        if (wave < 8) {
            float pv = b2v;
#pragma unroll
            for (int w = 0; w < 16; ++w) pv += pp[w * 512 + ppbase];
            const int half = lane & 32;
            float meanv = __shfl(pv, half + ((pc + 10) & 31), 64);
            float lsigv = __shfl(pv, half + ((pc + 20) & 31), 64);
            float e1, e2;
            if (pc < 10) {
                float ztar = zbuf[(t + 1) * 16 + pr];
                float invs = __expf(-lsigv);
                float dd = (ztar - meanv) * invs;
                e1 = -0.5f * dd * dd - lsigv - 0.91893853320467274f + pv;
                e2 = pv;
            } else { e1 = -FLT_MAX; e2 = -FLT_MAX; }
            float m1 = e1, m2 = e2;
#pragma unroll
            for (int off = 16; off > 0; off >>= 1) {
                m1 = fmaxf(m1, __shfl_xor(m1, off, 64));
                m2 = fmaxf(m2, __shfl_xor(m2, off, 64));
            }
            float s1 = (pc < 10) ? __expf(e1 - m1) : 0.0f;
            float s2 = (pc < 10) ? __expf(e2 - m2) : 0.0f;
#pragma unroll
            for (int off = 16; off > 0; off >>= 1) {
                s1 += __shfl_xor(s1, off, 64);
                s2 += __shfl_xor(s2, off, 64);
            }
            float ll = (m1 + __logf(s1)) - (m2 + __logf(s2));
            llacc += ll * mbuf[pr * 112 + t];
        }
    }
    if (wave < 8 && pc == 0) out[rowBase + pr] = llacc;
}

extern "C" void kernel_launch(void* const* d_in, const int* in_sizes, int n_in,
                              void* d_out, int out_size, void* d_ws, size_t ws_size,
                              hipStream_t stream) {
    const float* z   = (const float*)d_in[0];
    const float* c   = (const float*)d_in[1];
    const float* b   = (const float*)d_in[2];
    const float* m   = (const float*)d_in[3];
    const float* Wih = (const float*)d_in[4];
    const float* Whh = (const float*)d_in[5];
    const float* bih = (const float*)d_in[6];
    const float* bhh = (const float*)d_in[7];
    const float* W0  = (const float*)d_in[8];
    const float* b0  = (const float*)d_in[9];
    const float* W1  = (const float*)d_in[10];
    const float* b1  = (const float*)d_in[11];
    const float* W2  = (const float*)d_in[12];
    const float* b2  = (const float*)d_in[13];
    float* out = (float*)d_out;

    float* ws        = (float*)d_ws;
    float* constbuf  = ws;                                   // B*536
    float* gi_const  = constbuf + (size_t)BN * CW;           // B*1536 row-major
    float* mlp_const = gi_const + (size_t)BN * G3;           // B*512
    float* maskbuf   = mlp_const + (size_t)BN * HIDD;        // B*112
    unsigned short* WhhP = (unsigned short*)(maskbuf + (size_t)BN * DD);
    unsigned short* W0hP = WhhP + (size_t)96 * 16 * 512;
    unsigned short* W1P  = W0hP + (size_t)32 * 16 * 512;
    unsigned short* W2P  = W1P  + (size_t)32 * 16 * 512;
    float* hstate        = (float*)(W2P + (size_t)2 * 16 * 512);   // B*512 fp32
    unsigned short* h2g  = (unsigned short*)(hstate + (size_t)BN * HH);

    const size_t base = (size_t)BN * (CW + G3 + HIDD + DD) * 4
                      + (size_t)(96 + 32 + 32 + 2) * 16 * 512 * 2
                      + (size_t)BN * HH * 4;
    const size_t slab_per_t = (size_t)BN * 512 * 2;
    int TC = 0;
    if (ws_size > base) {
        TC = (int)((ws_size - base) / slab_per_t);
        TC = (TC / 16) * 16;
        if (TC > DD) TC = DD;   // 112 is a multiple of 16
    }

    // shared pre-pass
    build_const<<<(BN * CW + 255) / 256, 256, 0, stream>>>(c, b, m, constbuf);
    dim3 g1(BN / 64, G3 / 64);
    gemm_bias<<<g1, 256, 0, stream>>>(constbuf, Wih + G3, bih, gi_const, G3);
    dim3 g2(BN / 64, HIDD / 64);
    gemm_bias<<<g2, 256, 0, stream>>>(constbuf, W0 + (size_t)HH * HIDD, b0, mlp_const, HIDD);
    sort_mask<<<BN, 128, 0, stream>>>(b, m, maskbuf);
    pack_w<<<96 * 16, 64, 0, stream>>>(Whh, WhhP, 16, G3, G3);
    pack_w<<<32 * 16, 64, 0, stream>>>(W0,  W0hP, 16, HIDD, HIDD);
    pack_w<<<32 * 16, 64, 0, stream>>>(W1,  W1P,  16, HIDD, HIDD);
    pack_w<<<2 * 16, 64, 0, stream>>>(W2,  W2P,  16, 30, 30);

    if (TC >= 16) {
        zero_f32<<<(BN * HH + 255) / 256, 256, 0, stream>>>(hstate, BN * HH);
        zero_f32<<<(BN + 255) / 256, 256, 0, stream>>>(out, BN);
        for (int t0 = 0; t0 < DD; t0 += TC) {
            int tlen = DD - t0 < TC ? DD - t0 : TC;   // always a multiple of 16
            gru_rec_chunk<<<BN / 16, 1024, 0, stream>>>(z, Wih, bhh, gi_const, WhhP,
                                                        hstate, h2g, t0, tlen);
            dim3 gh(BN / 2, tlen / 16);
            head_mdn<<<gh, 1024, 0, stream>>>(z, b1, b2, mlp_const, maskbuf, h2g,
                                              W0hP, W1P, W2P, out, t0);
        }
    } else {
        gru_mfma_r5<<<BN / 16, 1024, 0, stream>>>(z, Wih, bhh, b1, b2, gi_const,
                                                  mlp_const, maskbuf, WhhP, W0hP, W1P, W2P, out);
    }
}

// Round 9
// 2642.174 us; speedup vs baseline: 1.7146x; 1.1246x over previous
//
#include <hip/hip_runtime.h>
#include <hip/hip_bf16.h>
#include <float.h>
#include <math.h>

#define BN   4096
#define DD   112
#define HH   512
#define G3   1536
#define CW   536
#define CWP  544     // K padded to 17*32
#define HIDD 512

typedef __attribute__((ext_vector_type(8))) short short8;
typedef __attribute__((ext_vector_type(4))) float float4v;

__device__ __forceinline__ unsigned short f2bf(float x) {
    __hip_bfloat16 h = __float2bfloat16(x);
    return *(unsigned short*)&h;
}

// ---------------- const = [c | b | m | 0pad]  (B x 544) bf16 ----------------
__global__ void build_constbf(const float* __restrict__ c, const float* __restrict__ b,
                              const float* __restrict__ m, unsigned short* __restrict__ out) {
    int idx = blockIdx.x * blockDim.x + threadIdx.x;
    if (idx >= BN * CWP) return;
    int row = idx / CWP, col = idx - row * CWP;
    float v;
    if (col < 312)      v = c[row * 312 + col];
    else if (col < 424) v = b[row * 112 + (col - 312)];
    else if (col < 536) v = m[row * 112 + (col - 424)];
    else                v = 0.0f;
    out[idx] = f2bf(v);
}

__global__ void zero_f32(float* __restrict__ p, int n) {
    int i = blockIdx.x * blockDim.x + threadIdx.x;
    if (i < n) p[i] = 0.0f;
}

// ---------------- pack weight [K][N] -> MFMA B-fragments (zero-padded) ----------------
// layout dst[nt][kc][lane][8]: lane holds B[k=kc*32+quad*8+j][n=nt*16+(lane&15)]
__global__ void pack_wN(const float* __restrict__ src, unsigned short* __restrict__ dst,
                        int kchunks, int ldn, int ncols, int nrows) {
    int bid = blockIdx.x;
    int nt = bid / kchunks, kc = bid - nt * kchunks;
    int lane = threadIdx.x;
    int quad = lane >> 4, l16 = lane & 15;
    int n = nt * 16 + l16;
    unsigned short v[8];
#pragma unroll
    for (int j = 0; j < 8; ++j) {
        int k = kc * 32 + quad * 8 + j;
        float f = (k < nrows && n < ncols) ? src[(size_t)k * ldn + n] : 0.0f;
        v[j] = f2bf(f);
    }
    unsigned short* p = dst + ((size_t)bid * 64 + lane) * 8;
#pragma unroll
    for (int j = 0; j < 8; ++j) p[j] = v[j];
}

// ---------------- bf16 MFMA GEMM: C[B x N] = A[B x 544] @ Wp + bias ----------------
// grid BN/16, block 1024 (16 waves); wave w owns tiles {w+16*i}, i<TPW. K = 17 chunks.
template<int TPW>
__global__ __launch_bounds__(1024) void gemm_const_mfma(
    const unsigned short* __restrict__ A, const unsigned short* __restrict__ BP,
    const float* __restrict__ bias, float* __restrict__ C, int N)
{
    const int tid = threadIdx.x;
    const int wave = tid >> 6, lane = tid & 63;
    const int quad = lane >> 4, l16 = lane & 15;
    const int rowBase = blockIdx.x * 16;
    const short8* BF = (const short8*)BP;
    float4v acc[TPW];
#pragma unroll
    for (int i = 0; i < TPW; ++i) {
        float bv = bias[(wave + 16 * i) * 16 + l16];
        acc[i] = (float4v){bv, bv, bv, bv};
    }
#pragma unroll 4
    for (int kc = 0; kc < 17; ++kc) {
        short8 af = *(const short8*)&A[(size_t)(rowBase + l16) * CWP + kc * 32 + quad * 8];
#pragma unroll
        for (int i = 0; i < TPW; ++i) {
            int tile = wave + 16 * i;
            acc[i] = __builtin_amdgcn_mfma_f32_16x16x32_bf16(af, BF[(tile * 17 + kc) * 64 + lane], acc[i], 0, 0, 0);
        }
    }
#pragma unroll
    for (int i = 0; i < TPW; ++i) {
        int col = (wave + 16 * i) * 16 + l16;
#pragma unroll
        for (int rg = 0; rg < 4; ++rg)
            C[(size_t)(rowBase + quad * 4 + rg) * N + col] = acc[i][rg];
    }
}

// ---------------- mask = descending sort of m*(1-b) per row ----------------
__global__ void sort_mask(const float* __restrict__ b, const float* __restrict__ m,
                          float* __restrict__ maskbuf) {
    __shared__ float s[128];
    const int row = blockIdx.x, t = threadIdx.x;
    float v = -FLT_MAX;
    if (t < DD) v = m[row * DD + t] * (1.0f - b[row * DD + t]);
    s[t] = v;
    __syncthreads();
    for (int k = 2; k <= 128; k <<= 1) {
        for (int j = k >> 1; j > 0; j >>= 1) {
            int ixj = t ^ j;
            if (ixj > t) {
                bool up = ((t & k) == 0);
                float a = s[t], bb = s[ixj];
                if ((a > bb) == up) { s[t] = bb; s[ixj] = a; }
            }
            __syncthreads();
        }
    }
    if (t < DD) maskbuf[row * DD + t] = s[127 - t];
}

// ================= KERNEL A: GRU recurrence chunk, dbuf h, 1 barrier/step =================
__global__ __launch_bounds__(1024, 4) void gru_rec_chunk(
    const float* __restrict__ z, const float* __restrict__ Wih,
    const float* __restrict__ bhh, const float* __restrict__ gi_const,
    const unsigned short* __restrict__ WhhP,
    float* __restrict__ hstate, unsigned short* __restrict__ h2g,
    int t0, int tlen)
{
    __shared__ unsigned short h_bf[2][16 * 520];
    __shared__ float zbuf[113 * 16];

    const int tid = threadIdx.x;
    const int wave = tid >> 6, lane = tid & 63;
    const int quad = lane >> 4, l16 = lane & 15;
    const int rowBase = blockIdx.x * 16;

    for (int idx = tid; idx < 113 * 16; idx += 1024) {
        int tt = idx >> 4, r = idx & 15;
        zbuf[idx] = (tt == 0) ? -1.0f : z[(rowBase + r) * DD + tt - 1];
    }

    int hcol[2];
    float wz0[2], wz1[2], wz2[2], bh2r[2];
    float gic0[2][4], gic1[2][4], gic2[2][4];
    float h_own[2][4];
#pragma unroll
    for (int i = 0; i < 2; ++i) {
        int tile = wave + 16 * i;
        int hc = tile * 16 + l16;
        hcol[i] = hc;
        wz0[i] = Wih[hc]; wz1[i] = Wih[512 + hc]; wz2[i] = Wih[1024 + hc];
        float bh0 = bhh[hc], bh1 = bhh[512 + hc];
        bh2r[i] = bhh[1024 + hc];
#pragma unroll
        for (int rg = 0; rg < 4; ++rg) {
            int m = quad * 4 + rg;
            const float* g = gi_const + (size_t)(rowBase + m) * G3;
            gic0[i][rg] = g[hc] + bh0;
            gic1[i][rg] = g[512 + hc] + bh1;
            gic2[i][rg] = g[1024 + hc];
            float hv = hstate[(size_t)(rowBase + m) * HH + hc];
            h_own[i][rg] = hv;
            h_bf[0][m * 520 + hc] = f2bf(hv);
        }
    }
    const short8* WhhF = (const short8*)WhhP;
    __syncthreads();

    for (int tt = 0; tt < tlen; ++tt) {
        const int t = t0 + tt;
        const int p = tt & 1;
        const unsigned short* hsrc = h_bf[p];
        unsigned short* hdst = h_bf[p ^ 1];
        float4v accR[2], accU[2], accN[2];
#pragma unroll
        for (int i = 0; i < 2; ++i) {
            accR[i] = (float4v){gic0[i][0], gic0[i][1], gic0[i][2], gic0[i][3]};
            accU[i] = (float4v){gic1[i][0], gic1[i][1], gic1[i][2], gic1[i][3]};
            accN[i] = (float4v){0.f, 0.f, 0.f, 0.f};
        }
#pragma unroll 8
        for (int kc = 0; kc < 16; ++kc) {
            short8 af = *(const short8*)&hsrc[l16 * 520 + kc * 32 + quad * 8];
#pragma unroll
            for (int i = 0; i < 2; ++i) {
                int tile = wave + 16 * i;
                accR[i] = __builtin_amdgcn_mfma_f32_16x16x32_bf16(af, WhhF[(tile * 16 + kc) * 64 + lane], accR[i], 0, 0, 0);
                accU[i] = __builtin_amdgcn_mfma_f32_16x16x32_bf16(af, WhhF[((tile + 32) * 16 + kc) * 64 + lane], accU[i], 0, 0, 0);
                accN[i] = __builtin_amdgcn_mfma_f32_16x16x32_bf16(af, WhhF[((tile + 64) * 16 + kc) * 64 + lane], accN[i], 0, 0, 0);
            }
        }
        // nonlin: reads regs, writes OTHER buffer -> no barrier before writes
#pragma unroll
        for (int i = 0; i < 2; ++i) {
#pragma unroll
            for (int rg = 0; rg < 4; ++rg) {
                int m = quad * 4 + rg;
                float zt = zbuf[t * 16 + m];
                float r = 1.0f / (1.0f + __expf(-(accR[i][rg] + zt * wz0[i])));
                float u = 1.0f / (1.0f + __expf(-(accU[i][rg] + zt * wz1[i])));
                float xn = gic2[i][rg] + zt * wz2[i] + r * (accN[i][rg] + bh2r[i]);
                float n = 1.0f - 2.0f / (__expf(2.0f * xn) + 1.0f);
                float h2 = (1.0f - u) * n + u * h_own[i][rg];
                h_own[i][rg] = h2;
                hdst[m * 520 + hcol[i]] = f2bf(h2);
            }
        }
        __syncthreads();  // single barrier: hdst complete; safe to read (store + next MFMA)
        {
            int col = lane * 8;
            uint4 v = *(const uint4*)&hdst[wave * 520 + col];
            *(uint4*)&h2g[((size_t)tt * BN + rowBase + wave) * 512 + col] = v;
        }
    }
#pragma unroll
    for (int i = 0; i < 2; ++i)
#pragma unroll
        for (int rg = 0; rg < 4; ++rg)
            hstate[(size_t)(rowBase + quad * 4 + rg) * HH + hcol[i]] = h_own[i][rg];
}

// ================= KERNEL B: MLP head + MDN, M=64 (4 b-rows x 16 timesteps) =================
// grid (BN/4, tlen/16), 1024 threads = 16 waves. LDS aliased: h->a2 ; a1->pp.
__global__ __launch_bounds__(1024) void head_mdn64(
    const float* __restrict__ z, const float* __restrict__ b1,
    const float* __restrict__ b2, const float* __restrict__ mlp_const,
    const float* __restrict__ maskbuf, const unsigned short* __restrict__ h2g,
    const unsigned short* __restrict__ W0hP, const unsigned short* __restrict__ W1P,
    const unsigned short* __restrict__ W2P, float* __restrict__ out, int t0)
{
    __shared__ unsigned short h_bf[64 * 520];   // h2, later a2
    __shared__ unsigned short a_bf[64 * 520];   // a1, later pp (float alias)
    float* ppf = (float*)a_bf;

    const int tid = threadIdx.x;
    const int wave = tid >> 6, lane = tid & 63;
    const int quad = lane >> 4, l16 = lane & 15;
    const int pr = tid >> 5, pc = tid & 31;
    const int b0 = blockIdx.x * 4;
    const int tg = blockIdx.y;

    // stage h2 tile: row r = bsub*16 + toff <-> (b0+bsub, trel=tg*16+toff); 32 shorts/thread
    {
        int flat = tid * 32;
        int r = flat >> 9, col = flat & 511;
        int bb = b0 + (r >> 4), trel = tg * 16 + (r & 15);
        const uint4* src = (const uint4*)&h2g[((size_t)trel * BN + bb) * 512 + col];
        uint4 v0 = src[0], v1 = src[1], v2 = src[2], v3 = src[3];
        uint4* dst = (uint4*)&h_bf[r * 520 + col];
        dst[0] = v0; dst[1] = v1; dst[2] = v2; dst[3] = v3;
    }
    int hcol[2];
    float b1c[2], mlc[2][4];
#pragma unroll
    for (int i = 0; i < 2; ++i) {
        int hc = (wave + 16 * i) * 16 + l16;
        hcol[i] = hc;
        b1c[i] = b1[hc];
#pragma unroll
        for (int mt = 0; mt < 4; ++mt) mlc[i][mt] = mlp_const[(size_t)(b0 + mt) * HIDD + hc];
    }
    const float b2v = (pc < 30) ? b2[pc] : 0.0f;
    const short8* W0hF = (const short8*)W0hP;
    const short8* W1F  = (const short8*)W1P;
    const short8* W2F  = (const short8*)W2P;
    __syncthreads();  // S0: h staged

    // ---- a1 = tanh(h2 @ W0h + mlc[b]) : 2 n-tiles x 4 m-tiles per wave ----
    float4v acc1[2][4];
#pragma unroll
    for (int i = 0; i < 2; ++i)
#pragma unroll
        for (int mt = 0; mt < 4; ++mt)
            acc1[i][mt] = (float4v){mlc[i][mt], mlc[i][mt], mlc[i][mt], mlc[i][mt]};
#pragma unroll 2
    for (int kc = 0; kc < 16; ++kc) {
        short8 af[4];
#pragma unroll
        for (int mt = 0; mt < 4; ++mt)
            af[mt] = *(const short8*)&h_bf[(mt * 16 + l16) * 520 + kc * 32 + quad * 8];
#pragma unroll
        for (int i = 0; i < 2; ++i) {
            short8 bf = W0hF[((wave + 16 * i) * 16 + kc) * 64 + lane];
#pragma unroll
            for (int mt = 0; mt < 4; ++mt)
                acc1[i][mt] = __builtin_amdgcn_mfma_f32_16x16x32_bf16(af[mt], bf, acc1[i][mt], 0, 0, 0);
        }
    }
#pragma unroll
    for (int i = 0; i < 2; ++i)
#pragma unroll
        for (int mt = 0; mt < 4; ++mt)
#pragma unroll
            for (int rg = 0; rg < 4; ++rg) {
                int m = mt * 16 + quad * 4 + rg;
                float x = acc1[i][mt][rg];
                a_bf[m * 520 + hcol[i]] = f2bf(1.0f - 2.0f / (__expf(2.0f * x) + 1.0f));
            }
    __syncthreads();  // S1: a1 ready
    // ---- a2 = tanh(a1 @ W1 + b1) ----
    float4v acc2[2][4];
#pragma unroll
    for (int i = 0; i < 2; ++i)
#pragma unroll
        for (int mt = 0; mt < 4; ++mt)
            acc2[i][mt] = (float4v){b1c[i], b1c[i], b1c[i], b1c[i]};
#pragma unroll 2
    for (int kc = 0; kc < 16; ++kc) {
        short8 af[4];
#pragma unroll
        for (int mt = 0; mt < 4; ++mt)
            af[mt] = *(const short8*)&a_bf[(mt * 16 + l16) * 520 + kc * 32 + quad * 8];
#pragma unroll
        for (int i = 0; i < 2; ++i) {
            short8 bf = W1F[((wave + 16 * i) * 16 + kc) * 64 + lane];
#pragma unroll
            for (int mt = 0; mt < 4; ++mt)
                acc2[i][mt] = __builtin_amdgcn_mfma_f32_16x16x32_bf16(af[mt], bf, acc2[i][mt], 0, 0, 0);
        }
    }
    __syncthreads();  // S2: a1 reads done (a_bf free for pp); h_bf free for a2
#pragma unroll
    for (int i = 0; i < 2; ++i)
#pragma unroll
        for (int mt = 0; mt < 4; ++mt)
#pragma unroll
            for (int rg = 0; rg < 4; ++rg) {
                int m = mt * 16 + quad * 4 + rg;
                float x = acc2[i][mt][rg];
                h_bf[m * 520 + hcol[i]] = f2bf(1.0f - 2.0f / (__expf(2.0f * x) + 1.0f));
            }
    __syncthreads();  // S3: a2 ready
    // ---- p = a2 @ W2 + b2 : wave -> mt = w>>2, kc group (w&3)*4..+3; 2 n-tiles ----
    {
        const int mtw = wave >> 2, kg = wave & 3;
        float4v ap0 = (float4v){0.f, 0.f, 0.f, 0.f}, ap1 = (float4v){0.f, 0.f, 0.f, 0.f};
#pragma unroll
        for (int kk = 0; kk < 4; ++kk) {
            int kc = kg * 4 + kk;
            short8 af = *(const short8*)&h_bf[(mtw * 16 + l16) * 520 + kc * 32 + quad * 8];
            ap0 = __builtin_amdgcn_mfma_f32_16x16x32_bf16(af, W2F[(0 * 16 + kc) * 64 + lane], ap0, 0, 0, 0);
            ap1 = __builtin_amdgcn_mfma_f32_16x16x32_bf16(af, W2F[(1 * 16 + kc) * 64 + lane], ap1, 0, 0, 0);
        }
        // pp[((kg*4+mt)*2+nt)*256 + lane*4 + rg]
#pragma unroll
        for (int rg = 0; rg < 4; ++rg) {
            ppf[((kg * 4 + mtw) * 2 + 0) * 256 + lane * 4 + rg] = ap0[rg];
            ppf[((kg * 4 + mtw) * 2 + 1) * 256 + lane * 4 + rg] = ap1[rg];
        }
    }
    __syncthreads();  // S4: partials ready
    // ---- reduce + MDN logsumexp for 2 row-slots/thread-group ----
    float llm[2];
#pragma unroll
    for (int rh = 0; rh < 2; ++rh) {
        const int slot = rh * 32 + pr;               // row m of GEMM
        const int bsub = slot >> 4, toff = slot & 15;
        const int mm = slot & 15;
        const int lane_c = ((mm >> 2) * 16 + (pc & 15));
        const int rgc = mm & 3, ntv = pc >> 4;
        float pv = b2v;
#pragma unroll
        for (int kg = 0; kg < 4; ++kg)
            pv += ppf[((kg * 4 + bsub) * 2 + ntv) * 256 + lane_c * 4 + rgc];
        const int half = lane & 32;
        float meanv = __shfl(pv, half + ((pc + 10) & 31), 64);
        float lsigv = __shfl(pv, half + ((pc + 20) & 31), 64);
        float e1, e2;
        if (pc < 10) {
            float ztar = z[(size_t)(b0 + bsub) * DD + t0 + tg * 16 + toff];
            float invs = __expf(-lsigv);
            float dd = (ztar - meanv) * invs;
            e1 = -0.5f * dd * dd - lsigv - 0.91893853320467274f + pv;
            e2 = pv;
        } else { e1 = -FLT_MAX; e2 = -FLT_MAX; }
        float m1 = e1, m2 = e2;
#pragma unroll
        for (int off = 16; off > 0; off >>= 1) {
            m1 = fmaxf(m1, __shfl_xor(m1, off, 64));
            m2 = fmaxf(m2, __shfl_xor(m2, off, 64));
        }
        float s1 = (pc < 10) ? __expf(e1 - m1) : 0.0f;
        float s2 = (pc < 10) ? __expf(e2 - m2) : 0.0f;
#pragma unroll
        for (int off = 16; off > 0; off >>= 1) {
            s1 += __shfl_xor(s1, off, 64);
            s2 += __shfl_xor(s2, off, 64);
        }
        float ll = (m1 + __logf(s1)) - (m2 + __logf(s2));
        llm[rh] = ll * maskbuf[(size_t)(b0 + bsub) * DD + t0 + tg * 16 + toff];
    }
    __syncthreads();  // S5: pp reads done before slot writes
    if (pc == 0) { ppf[pr] = llm[0]; ppf[32 + pr] = llm[1]; }
    __syncthreads();  // S6
    if (tid < 4) {
        float s = 0.0f;
#pragma unroll
        for (int j = 0; j < 16; ++j) s += ppf[tid * 16 + j];
        atomicAdd(&out[b0 + tid], s);
    }
}

// ================= FALLBACK: R5-verified fused kernel (small workspace) =================
__global__ __launch_bounds__(1024, 4) void gru_mfma_r5(
    const float* __restrict__ z, const float* __restrict__ Wih,
    const float* __restrict__ bhh, const float* __restrict__ b1,
    const float* __restrict__ b2,
    const float* __restrict__ gi_const, const float* __restrict__ mlp_const,
    const float* __restrict__ maskbuf,
    const unsigned short* __restrict__ WhhP, const unsigned short* __restrict__ W0hP,
    const unsigned short* __restrict__ W1P, const unsigned short* __restrict__ W2P,
    float* __restrict__ out)
{
    __shared__ unsigned short h_bf[16 * 520];
    __shared__ unsigned short a_bf[16 * 520];
    __shared__ float pp[16 * 512];
    __shared__ float zbuf[113 * 16];
    __shared__ float mbuf[16 * 112];

    const int tid = threadIdx.x;
    const int wave = tid >> 6, lane = tid & 63;
    const int quad = lane >> 4, l16 = lane & 15;
    const int pr = tid >> 5, pc = tid & 31;
    const int rowBase = blockIdx.x * 16;

    for (int idx = tid; idx < 16 * 520; idx += 1024) h_bf[idx] = 0;
    for (int idx = tid; idx < 113 * 16; idx += 1024) {
        int tt = idx >> 4, r = idx & 15;
        zbuf[idx] = (tt == 0) ? -1.0f : z[(rowBase + r) * DD + tt - 1];
    }
    for (int idx = tid; idx < 16 * 112; idx += 1024) {
        int r = idx / DD, tt = idx - r * DD;
        mbuf[idx] = maskbuf[(rowBase + r) * DD + tt];
    }
    int hcol[2];
    float wz0[2], wz1[2], wz2[2], bh2r[2], b1c[2];
    float gic0[2][4], gic1[2][4], gic2[2][4], mlc[2][4];
    float h_own[2][4];
#pragma unroll
    for (int i = 0; i < 2; ++i) {
        int tile = wave + 16 * i;
        int hc = tile * 16 + l16;
        hcol[i] = hc;
        wz0[i] = Wih[hc]; wz1[i] = Wih[512 + hc]; wz2[i] = Wih[1024 + hc];
        float bh0 = bhh[hc], bh1 = bhh[512 + hc];
        bh2r[i] = bhh[1024 + hc];
        b1c[i] = b1[hc];
#pragma unroll
        for (int rg = 0; rg < 4; ++rg) {
            int m = quad * 4 + rg;
            const float* g = gi_const + (size_t)(rowBase + m) * G3;
            gic0[i][rg] = g[hc] + bh0;
            gic1[i][rg] = g[512 + hc] + bh1;
            gic2[i][rg] = g[1024 + hc];
            mlc[i][rg] = mlp_const[(size_t)(rowBase + m) * HIDD + hc];
            h_own[i][rg] = 0.0f;
        }
    }
    const float b2v = (pc < 30) ? b2[pc] : 0.0f;
    const int ppbase = (pc >> 4) * 256 + ((pr >> 2) * 16 + (pc & 15)) * 4 + (pr & 3);
    const short8* WhhF = (const short8*)WhhP;
    const short8* W0hF = (const short8*)W0hP;
    const short8* W1F  = (const short8*)W1P;
    const short8* W2F  = (const short8*)W2P;
    float llacc = 0.0f;
    __syncthreads();
    for (int t = 0; t < DD; ++t) {
        float4v accR[2], accU[2], accN[2];
#pragma unroll
        for (int i = 0; i < 2; ++i) {
            accR[i] = (float4v){gic0[i][0], gic0[i][1], gic0[i][2], gic0[i][3]};
            accU[i] = (float4v){gic1[i][0], gic1[i][1], gic1[i][2], gic1[i][3]};
            accN[i] = (float4v){0.f, 0.f, 0.f, 0.f};
        }
#pragma unroll 4
        for (int kc = 0; kc < 16; ++kc) {
            short8 af = *(const short8*)&h_bf[l16 * 520 + kc * 32 + quad * 8];
#pragma unroll
            for (int i = 0; i < 2; ++i) {
                int tile = wave + 16 * i;
                accR[i] = __builtin_amdgcn_mfma_f32_16x16x32_bf16(af, WhhF[(tile * 16 + kc) * 64 + lane], accR[i], 0, 0, 0);
                accU[i] = __builtin_amdgcn_mfma_f32_16x16x32_bf16(af, WhhF[((tile + 32) * 16 + kc) * 64 + lane], accU[i], 0, 0, 0);
                accN[i] = __builtin_amdgcn_mfma_f32_16x16x32_bf16(af, WhhF[((tile + 64) * 16 + kc) * 64 + lane], accN[i], 0, 0, 0);
            }
        }
        __syncthreads();
#pragma unroll
        for (int i = 0; i < 2; ++i) {
#pragma unroll
            for (int rg = 0; rg < 4; ++rg) {
                int m = quad * 4 + rg;
                float zt = zbuf[t * 16 + m];
                float r = 1.0f / (1.0f + __expf(-(accR[i][rg] + zt * wz0[i])));
                float u = 1.0f / (1.0f + __expf(-(accU[i][rg] + zt * wz1[i])));
                float xn = gic2[i][rg] + zt * wz2[i] + r * (accN[i][rg] + bh2r[i]);
                float n = 1.0f - 2.0f / (__expf(2.0f * xn) + 1.0f);
                float h2 = (1.0f - u) * n + u * h_own[i][rg];
                h_own[i][rg] = h2;
                h_bf[m * 520 + hcol[i]] = f2bf(h2);
            }
        }
        __syncthreads();
        float4v acc1[2];
#pragma unroll
        for (int i = 0; i < 2; ++i) acc1[i] = (float4v){mlc[i][0], mlc[i][1], mlc[i][2], mlc[i][3]};
#pragma unroll 4
        for (int kc = 0; kc < 16; ++kc) {
            short8 af = *(const short8*)&h_bf[l16 * 520 + kc * 32 + quad * 8];
#pragma unroll
            for (int i = 0; i < 2; ++i)
                acc1[i] = __builtin_amdgcn_mfma_f32_16x16x32_bf16(af, W0hF[((wave + 16 * i) * 16 + kc) * 64 + lane], acc1[i], 0, 0, 0);
        }
#pragma unroll
        for (int i = 0; i < 2; ++i)
#pragma unroll
            for (int rg = 0; rg < 4; ++rg) {
                int m = quad * 4 + rg;
                float x = acc1[i][rg];
                a_bf[m * 520 + hcol[i]] = f2bf(1.0f - 2.0f / (__expf(2.0f * x) + 1.0f));
            }
        __syncthreads();
        float4v acc2[2];
#pragma unroll
        for (int i = 0; i < 2; ++i) acc2[i] = (float4v){b1c[i], b1c[i], b1c[i], b1c[i]};
#pragma unroll 4
        for (int kc = 0; kc < 16; ++kc) {
            short8 af = *(const short8*)&a_bf[l16 * 520 + kc * 32 + quad * 8];
#pragma unroll
            for (int i = 0; i < 2; ++i)
                acc2[i] = __builtin_amdgcn_mfma_f32_16x16x32_bf16(af, W1F[((wave + 16 * i) * 16 + kc) * 64 + lane], acc2[i], 0, 0, 0);
        }
        __syncthreads();
#pragma unroll
        for (int i = 0; i < 2; ++i)
#pragma unroll
            for (int rg = 0; rg < 4; ++rg) {
                int m = quad * 4 + rg;
                float x = acc2[i][rg];
                a_bf[m * 520 + hcol[i]] = f2bf(1.0f - 2.0f / (__expf(2.0f * x) + 1.0f));
            }
        __syncthreads();
        {
            int kc = wave;
            short8 af = *(const short8*)&a_bf[l16 * 520 + kc * 32 + quad * 8];
            float4v ap0 = (float4v){0.f, 0.f, 0.f, 0.f}, ap1 = (float4v){0.f, 0.f, 0.f, 0.f};
            ap0 = __builtin_amdgcn_mfma_f32_16x16x32_bf16(af, W2F[(0 * 16 + kc) * 64 + lane], ap0, 0, 0, 0);
            ap1 = __builtin_amdgcn_mfma_f32_16x16x32_bf16(af, W2F[(1 * 16 + kc) * 64 + lane], ap1, 0, 0, 0);
#pragma unroll
            for (int rg = 0; rg < 4; ++rg) {
                pp[wave * 512 + 0 * 256 + lane * 4 + rg] = ap0[rg];
                pp[wave * 512 + 1 * 256 + lane * 4 + rg] = ap1[rg];
            }
        }
        __syncthreads();
        if (wave < 8) {
            float pv = b2v;
#pragma unroll
            for (int w = 0; w < 16; ++w) pv += pp[w * 512 + ppbase];
            const int half = lane & 32;
            float meanv = __shfl(pv, half + ((pc + 10) & 31), 64);
            float lsigv = __shfl(pv, half + ((pc + 20) & 31), 64);
            float e1, e2;
            if (pc < 10) {
                float ztar = zbuf[(t + 1) * 16 + pr];
                float invs = __expf(-lsigv);
                float dd = (ztar - meanv) * invs;
                e1 = -0.5f * dd * dd - lsigv - 0.91893853320467274f + pv;
                e2 = pv;
            } else { e1 = -FLT_MAX; e2 = -FLT_MAX; }
            float m1 = e1, m2 = e2;
#pragma unroll
            for (int off = 16; off > 0; off >>= 1) {
                m1 = fmaxf(m1, __shfl_xor(m1, off, 64));
                m2 = fmaxf(m2, __shfl_xor(m2, off, 64));
            }
            float s1 = (pc < 10) ? __expf(e1 - m1) : 0.0f;
            float s2 = (pc < 10) ? __expf(e2 - m2) : 0.0f;
#pragma unroll
            for (int off = 16; off > 0; off >>= 1) {
                s1 += __shfl_xor(s1, off, 64);
                s2 += __shfl_xor(s2, off, 64);
            }
            float ll = (m1 + __logf(s1)) - (m2 + __logf(s2));
            llacc += ll * mbuf[pr * 112 + t];
        }
    }
    if (wave < 8 && pc == 0) out[rowBase + pr] = llacc;
}

extern "C" void kernel_launch(void* const* d_in, const int* in_sizes, int n_in,
                              void* d_out, int out_size, void* d_ws, size_t ws_size,
                              hipStream_t stream) {
    const float* z   = (const float*)d_in[0];
    const float* c   = (const float*)d_in[1];
    const float* b   = (const float*)d_in[2];
    const float* m   = (const float*)d_in[3];
    const float* Wih = (const float*)d_in[4];
    const float* Whh = (const float*)d_in[5];
    const float* bih = (const float*)d_in[6];
    const float* bhh = (const float*)d_in[7];
    const float* W0  = (const float*)d_in[8];
    const float* b0  = (const float*)d_in[9];
    const float* W1  = (const float*)d_in[10];
    const float* b1  = (const float*)d_in[11];
    const float* W2  = (const float*)d_in[12];
    const float* b2  = (const float*)d_in[13];
    float* out = (float*)d_out;

    char* p = (char*)d_ws;
    unsigned short* constbf = (unsigned short*)p;  p += (size_t)BN * CWP * 2;
    float* gi_const  = (float*)p;                  p += (size_t)BN * G3 * 4;
    float* mlp_const = (float*)p;                  p += (size_t)BN * HIDD * 4;
    float* maskbuf   = (float*)p;                  p += (size_t)BN * DD * 4;
    unsigned short* WihP = (unsigned short*)p;     p += (size_t)96 * 17 * 512 * 2;
    unsigned short* W0cP = (unsigned short*)p;     p += (size_t)32 * 17 * 512 * 2;
    unsigned short* WhhP = (unsigned short*)p;     p += (size_t)96 * 16 * 512 * 2;
    unsigned short* W0hP = (unsigned short*)p;     p += (size_t)32 * 16 * 512 * 2;
    unsigned short* W1P  = (unsigned short*)p;     p += (size_t)32 * 16 * 512 * 2;
    unsigned short* W2P  = (unsigned short*)p;     p += (size_t)2 * 16 * 512 * 2;
    float* hstate        = (float*)p;              p += (size_t)BN * HH * 4;
    unsigned short* h2g  = (unsigned short*)p;

    const size_t base = (size_t)(p - (char*)d_ws);
    const size_t slab_per_t = (size_t)BN * 512 * 2;
    int TC = 0;
    if (ws_size > base) {
        TC = (int)((ws_size - base) / slab_per_t);
        TC = (TC / 16) * 16;
        if (TC > DD) TC = DD;
    }

    // shared pre-pass (bf16 MFMA for the two const GEMMs)
    build_constbf<<<(BN * CWP + 255) / 256, 256, 0, stream>>>(c, b, m, constbf);
    pack_wN<<<96 * 17, 64, 0, stream>>>(Wih + G3, WihP, 17, G3, G3, CW);
    pack_wN<<<32 * 17, 64, 0, stream>>>(W0 + (size_t)HH * HIDD, W0cP, 17, HIDD, HIDD, CW);
    pack_wN<<<96 * 16, 64, 0, stream>>>(Whh, WhhP, 16, G3, G3, HH);
    pack_wN<<<32 * 16, 64, 0, stream>>>(W0,  W0hP, 16, HIDD, HIDD, HH);
    pack_wN<<<32 * 16, 64, 0, stream>>>(W1,  W1P,  16, HIDD, HIDD, HH);
    pack_wN<<<2 * 16, 64, 0, stream>>>(W2,  W2P,  16, 30, 30, HH);
    gemm_const_mfma<6><<<BN / 16, 1024, 0, stream>>>(constbf, WihP, bih, gi_const, G3);
    gemm_const_mfma<2><<<BN / 16, 1024, 0, stream>>>(constbf, W0cP, b0, mlp_const, HIDD);
    sort_mask<<<BN, 128, 0, stream>>>(b, m, maskbuf);

    if (TC >= 16) {
        zero_f32<<<(BN * HH + 255) / 256, 256, 0, stream>>>(hstate, BN * HH);
        zero_f32<<<(BN + 255) / 256, 256, 0, stream>>>(out, BN);
        for (int t0 = 0; t0 < DD; t0 += TC) {
            int tlen = DD - t0 < TC ? DD - t0 : TC;   // multiple of 16 (112 = 7*16)
            gru_rec_chunk<<<BN / 16, 1024, 0, stream>>>(z, Wih, bhh, gi_const, WhhP,
                                                        hstate, h2g, t0, tlen);
            dim3 gh(BN / 4, tlen / 16);
            head_mdn64<<<gh, 1024, 0, stream>>>(z, b1, b2, mlp_const, maskbuf, h2g,
                                                W0hP, W1P, W2P, out, t0);
        }
    } else {
        gru_mfma_r5<<<BN / 16, 1024, 0, stream>>>(z, Wih, bhh, b1, b2, gi_const,
                                                  mlp_const, maskbuf, WhhP, W0hP, W1P, W2P, out);
    }
}

// Round 10
// 2592.351 us; speedup vs baseline: 1.7476x; 1.0192x over previous
//
#include <hip/hip_runtime.h>
#include <hip/hip_bf16.h>
#include <float.h>
#include <math.h>

#define BN   4096
#define DD   112
#define HH   512
#define G3   1536
#define CW   536
#define CWP  544     // K padded to 17*32
#define HIDD 512

typedef __attribute__((ext_vector_type(8))) short short8;
typedef __attribute__((ext_vector_type(4))) float float4v;

__device__ __forceinline__ unsigned short f2bf(float x) {
    __hip_bfloat16 h = __float2bfloat16(x);
    return *(unsigned short*)&h;
}

// ---------------- const = [c | b | m | 0pad]  (B x 544) bf16 ----------------
__global__ void build_constbf(const float* __restrict__ c, const float* __restrict__ b,
                              const float* __restrict__ m, unsigned short* __restrict__ out) {
    int idx = blockIdx.x * blockDim.x + threadIdx.x;
    if (idx >= BN * CWP) return;
    int row = idx / CWP, col = idx - row * CWP;
    float v;
    if (col < 312)      v = c[row * 312 + col];
    else if (col < 424) v = b[row * 112 + (col - 312)];
    else if (col < 536) v = m[row * 112 + (col - 424)];
    else                v = 0.0f;
    out[idx] = f2bf(v);
}

__global__ void zero_f32(float* __restrict__ p, int n) {
    int i = blockIdx.x * blockDim.x + threadIdx.x;
    if (i < n) p[i] = 0.0f;
}

// ---------------- pack weight [K][N] -> MFMA B-fragments (zero-padded) ----------------
__global__ void pack_wN(const float* __restrict__ src, unsigned short* __restrict__ dst,
                        int kchunks, int ldn, int ncols, int nrows) {
    int bid = blockIdx.x;
    int nt = bid / kchunks, kc = bid - nt * kchunks;
    int lane = threadIdx.x;
    int quad = lane >> 4, l16 = lane & 15;
    int n = nt * 16 + l16;
    unsigned short v[8];
#pragma unroll
    for (int j = 0; j < 8; ++j) {
        int k = kc * 32 + quad * 8 + j;
        float f = (k < nrows && n < ncols) ? src[(size_t)k * ldn + n] : 0.0f;
        v[j] = f2bf(f);
    }
    unsigned short* p = dst + ((size_t)bid * 64 + lane) * 8;
#pragma unroll
    for (int j = 0; j < 8; ++j) p[j] = v[j];
}

// ---------------- bf16 MFMA GEMM: C[B x N] = A[B x 544] @ Wp + bias ----------------
template<int TPW>
__global__ __launch_bounds__(1024) void gemm_const_mfma(
    const unsigned short* __restrict__ A, const unsigned short* __restrict__ BP,
    const float* __restrict__ bias, float* __restrict__ C, int N)
{
    const int tid = threadIdx.x;
    const int wave = tid >> 6, lane = tid & 63;
    const int quad = lane >> 4, l16 = lane & 15;
    const int rowBase = blockIdx.x * 16;
    const short8* BF = (const short8*)BP;
    float4v acc[TPW];
#pragma unroll
    for (int i = 0; i < TPW; ++i) {
        float bv = bias[(wave + 16 * i) * 16 + l16];
        acc[i] = (float4v){bv, bv, bv, bv};
    }
#pragma unroll 4
    for (int kc = 0; kc < 17; ++kc) {
        short8 af = *(const short8*)&A[(size_t)(rowBase + l16) * CWP + kc * 32 + quad * 8];
#pragma unroll
        for (int i = 0; i < TPW; ++i) {
            int tile = wave + 16 * i;
            acc[i] = __builtin_amdgcn_mfma_f32_16x16x32_bf16(af, BF[(tile * 17 + kc) * 64 + lane], acc[i], 0, 0, 0);
        }
    }
#pragma unroll
    for (int i = 0; i < TPW; ++i) {
        int col = (wave + 16 * i) * 16 + l16;
#pragma unroll
        for (int rg = 0; rg < 4; ++rg)
            C[(size_t)(rowBase + quad * 4 + rg) * N + col] = acc[i][rg];
    }
}

// ---------------- mask = descending sort of m*(1-b) per row ----------------
__global__ void sort_mask(const float* __restrict__ b, const float* __restrict__ m,
                          float* __restrict__ maskbuf) {
    __shared__ float s[128];
    const int row = blockIdx.x, t = threadIdx.x;
    float v = -FLT_MAX;
    if (t < DD) v = m[row * DD + t] * (1.0f - b[row * DD + t]);
    s[t] = v;
    __syncthreads();
    for (int k = 2; k <= 128; k <<= 1) {
        for (int j = k >> 1; j > 0; j >>= 1) {
            int ixj = t ^ j;
            if (ixj > t) {
                bool up = ((t & k) == 0);
                float a = s[t], bb = s[ixj];
                if ((a > bb) == up) { s[t] = bb; s[ixj] = a; }
            }
            __syncthreads();
        }
    }
    if (t < DD) maskbuf[row * DD + t] = s[127 - t];
}

// ================= KERNEL A: GRU recurrence chunk, dbuf h, phase-staggered K-loop =================
__global__ __launch_bounds__(1024, 4) void gru_rec_chunk(
    const float* __restrict__ z, const float* __restrict__ Wih,
    const float* __restrict__ bhh, const float* __restrict__ gi_const,
    const unsigned short* __restrict__ WhhP,
    float* __restrict__ hstate, unsigned short* __restrict__ h2g,
    int t0, int tlen)
{
    __shared__ unsigned short h_bf[2][16 * 520];
    __shared__ float zbuf[113 * 16];

    const int tid = threadIdx.x;
    const int wave = tid >> 6, lane = tid & 63;
    const int quad = lane >> 4, l16 = lane & 15;
    const int rowBase = blockIdx.x * 16;
    const int phase = blockIdx.x & 15;   // de-phase L2 weight sweep across blocks

    for (int idx = tid; idx < 113 * 16; idx += 1024) {
        int tt = idx >> 4, r = idx & 15;
        zbuf[idx] = (tt == 0) ? -1.0f : z[(rowBase + r) * DD + tt - 1];
    }

    int hcol[2];
    float wz0[2], wz1[2], wz2[2], bh2r[2];
    float gic0[2][4], gic1[2][4], gic2[2][4];
    float h_own[2][4];
#pragma unroll
    for (int i = 0; i < 2; ++i) {
        int tile = wave + 16 * i;
        int hc = tile * 16 + l16;
        hcol[i] = hc;
        wz0[i] = Wih[hc]; wz1[i] = Wih[512 + hc]; wz2[i] = Wih[1024 + hc];
        float bh0 = bhh[hc], bh1 = bhh[512 + hc];
        bh2r[i] = bhh[1024 + hc];
#pragma unroll
        for (int rg = 0; rg < 4; ++rg) {
            int m = quad * 4 + rg;
            const float* g = gi_const + (size_t)(rowBase + m) * G3;
            gic0[i][rg] = g[hc] + bh0;
            gic1[i][rg] = g[512 + hc] + bh1;
            gic2[i][rg] = g[1024 + hc];
            float hv = hstate[(size_t)(rowBase + m) * HH + hc];
            h_own[i][rg] = hv;
            h_bf[0][m * 520 + hc] = f2bf(hv);
        }
    }
    const short8* WhhF = (const short8*)WhhP;
    __syncthreads();

    for (int tt = 0; tt < tlen; ++tt) {
        const int t = t0 + tt;
        const int p = tt & 1;
        const unsigned short* hsrc = h_bf[p];
        unsigned short* hdst = h_bf[p ^ 1];
        float4v accR[2], accU[2], accN[2];
#pragma unroll
        for (int i = 0; i < 2; ++i) {
            accR[i] = (float4v){gic0[i][0], gic0[i][1], gic0[i][2], gic0[i][3]};
            accU[i] = (float4v){gic1[i][0], gic1[i][1], gic1[i][2], gic1[i][3]};
            accN[i] = (float4v){0.f, 0.f, 0.f, 0.f};
        }
#pragma unroll 8
        for (int kk = 0; kk < 16; ++kk) {
            const int kc = (kk + phase) & 15;
            short8 af = *(const short8*)&hsrc[l16 * 520 + kc * 32 + quad * 8];
#pragma unroll
            for (int i = 0; i < 2; ++i) {
                int tile = wave + 16 * i;
                accR[i] = __builtin_amdgcn_mfma_f32_16x16x32_bf16(af, WhhF[(tile * 16 + kc) * 64 + lane], accR[i], 0, 0, 0);
                accU[i] = __builtin_amdgcn_mfma_f32_16x16x32_bf16(af, WhhF[((tile + 32) * 16 + kc) * 64 + lane], accU[i], 0, 0, 0);
                accN[i] = __builtin_amdgcn_mfma_f32_16x16x32_bf16(af, WhhF[((tile + 64) * 16 + kc) * 64 + lane], accN[i], 0, 0, 0);
            }
        }
#pragma unroll
        for (int i = 0; i < 2; ++i) {
#pragma unroll
            for (int rg = 0; rg < 4; ++rg) {
                int m = quad * 4 + rg;
                float zt = zbuf[t * 16 + m];
                float r = 1.0f / (1.0f + __expf(-(accR[i][rg] + zt * wz0[i])));
                float u = 1.0f / (1.0f + __expf(-(accU[i][rg] + zt * wz1[i])));
                float xn = gic2[i][rg] + zt * wz2[i] + r * (accN[i][rg] + bh2r[i]);
                float n = 1.0f - 2.0f / (__expf(2.0f * xn) + 1.0f);
                float h2 = (1.0f - u) * n + u * h_own[i][rg];
                h_own[i][rg] = h2;
                hdst[m * 520 + hcol[i]] = f2bf(h2);
            }
        }
        __syncthreads();  // single barrier: hdst complete
        {
            int col = lane * 8;
            uint4 v = *(const uint4*)&hdst[wave * 520 + col];
            *(uint4*)&h2g[((size_t)tt * BN + rowBase + wave) * 512 + col] = v;
        }
    }
#pragma unroll
    for (int i = 0; i < 2; ++i)
#pragma unroll
        for (int rg = 0; rg < 4; ++rg)
            hstate[(size_t)(rowBase + quad * 4 + rg) * HH + hcol[i]] = h_own[i][rg];
}

// ================= KERNEL B: MLP head + MDN, M=64, phase-staggered K-loops =================
__global__ __launch_bounds__(1024) void head_mdn64(
    const float* __restrict__ z, const float* __restrict__ b1,
    const float* __restrict__ b2, const float* __restrict__ mlp_const,
    const float* __restrict__ maskbuf, const unsigned short* __restrict__ h2g,
    const unsigned short* __restrict__ W0hP, const unsigned short* __restrict__ W1P,
    const unsigned short* __restrict__ W2P, float* __restrict__ out, int t0)
{
    __shared__ unsigned short h_bf[64 * 520];   // h2, later a2
    __shared__ unsigned short a_bf[64 * 520];   // a1, later pp (float alias)
    float* ppf = (float*)a_bf;

    const int tid = threadIdx.x;
    const int wave = tid >> 6, lane = tid & 63;
    const int quad = lane >> 4, l16 = lane & 15;
    const int pr = tid >> 5, pc = tid & 31;
    const int b0 = blockIdx.x * 4;
    const int tg = blockIdx.y;
    const int phase = blockIdx.x & 15;

    {
        int flat = tid * 32;
        int r = flat >> 9, col = flat & 511;
        int bb = b0 + (r >> 4), trel = tg * 16 + (r & 15);
        const uint4* src = (const uint4*)&h2g[((size_t)trel * BN + bb) * 512 + col];
        uint4 v0 = src[0], v1 = src[1], v2 = src[2], v3 = src[3];
        uint4* dst = (uint4*)&h_bf[r * 520 + col];
        dst[0] = v0; dst[1] = v1; dst[2] = v2; dst[3] = v3;
    }
    int hcol[2];
    float b1c[2], mlc[2][4];
#pragma unroll
    for (int i = 0; i < 2; ++i) {
        int hc = (wave + 16 * i) * 16 + l16;
        hcol[i] = hc;
        b1c[i] = b1[hc];
#pragma unroll
        for (int mt = 0; mt < 4; ++mt) mlc[i][mt] = mlp_const[(size_t)(b0 + mt) * HIDD + hc];
    }
    const float b2v = (pc < 30) ? b2[pc] : 0.0f;
    const short8* W0hF = (const short8*)W0hP;
    const short8* W1F  = (const short8*)W1P;
    const short8* W2F  = (const short8*)W2P;
    __syncthreads();  // S0: h staged

    // ---- a1 = tanh(h2 @ W0h + mlc[b]) ----
    float4v acc1[2][4];
#pragma unroll
    for (int i = 0; i < 2; ++i)
#pragma unroll
        for (int mt = 0; mt < 4; ++mt)
            acc1[i][mt] = (float4v){mlc[i][mt], mlc[i][mt], mlc[i][mt], mlc[i][mt]};
#pragma unroll 2
    for (int kk = 0; kk < 16; ++kk) {
        const int kc = (kk + phase) & 15;
        short8 af[4];
#pragma unroll
        for (int mt = 0; mt < 4; ++mt)
            af[mt] = *(const short8*)&h_bf[(mt * 16 + l16) * 520 + kc * 32 + quad * 8];
#pragma unroll
        for (int i = 0; i < 2; ++i) {
            short8 bf = W0hF[((wave + 16 * i) * 16 + kc) * 64 + lane];
#pragma unroll
            for (int mt = 0; mt < 4; ++mt)
                acc1[i][mt] = __builtin_amdgcn_mfma_f32_16x16x32_bf16(af[mt], bf, acc1[i][mt], 0, 0, 0);
        }
    }
#pragma unroll
    for (int i = 0; i < 2; ++i)
#pragma unroll
        for (int mt = 0; mt < 4; ++mt)
#pragma unroll
            for (int rg = 0; rg < 4; ++rg) {
                int m = mt * 16 + quad * 4 + rg;
                float x = acc1[i][mt][rg];
                a_bf[m * 520 + hcol[i]] = f2bf(1.0f - 2.0f / (__expf(2.0f * x) + 1.0f));
            }
    __syncthreads();  // S1: a1 ready
    // ---- a2 = tanh(a1 @ W1 + b1) ----
    float4v acc2[2][4];
#pragma unroll
    for (int i = 0; i < 2; ++i)
#pragma unroll
        for (int mt = 0; mt < 4; ++mt)
            acc2[i][mt] = (float4v){b1c[i], b1c[i], b1c[i], b1c[i]};
#pragma unroll 2
    for (int kk = 0; kk < 16; ++kk) {
        const int kc = (kk + phase) & 15;
        short8 af[4];
#pragma unroll
        for (int mt = 0; mt < 4; ++mt)
            af[mt] = *(const short8*)&a_bf[(mt * 16 + l16) * 520 + kc * 32 + quad * 8];
#pragma unroll
        for (int i = 0; i < 2; ++i) {
            short8 bf = W1F[((wave + 16 * i) * 16 + kc) * 64 + lane];
#pragma unroll
            for (int mt = 0; mt < 4; ++mt)
                acc2[i][mt] = __builtin_amdgcn_mfma_f32_16x16x32_bf16(af[mt], bf, acc2[i][mt], 0, 0, 0);
        }
    }
    __syncthreads();  // S2: a1 reads done
#pragma unroll
    for (int i = 0; i < 2; ++i)
#pragma unroll
        for (int mt = 0; mt < 4; ++mt)
#pragma unroll
            for (int rg = 0; rg < 4; ++rg) {
                int m = mt * 16 + quad * 4 + rg;
                float x = acc2[i][mt][rg];
                h_bf[m * 520 + hcol[i]] = f2bf(1.0f - 2.0f / (__expf(2.0f * x) + 1.0f));
            }
    __syncthreads();  // S3: a2 ready
    // ---- p = a2 @ W2 + b2 ----
    {
        const int mtw = wave >> 2, kg = wave & 3;
        float4v ap0 = (float4v){0.f, 0.f, 0.f, 0.f}, ap1 = (float4v){0.f, 0.f, 0.f, 0.f};
#pragma unroll
        for (int kk = 0; kk < 4; ++kk) {
            int kc = kg * 4 + kk;
            short8 af = *(const short8*)&h_bf[(mtw * 16 + l16) * 520 + kc * 32 + quad * 8];
            ap0 = __builtin_amdgcn_mfma_f32_16x16x32_bf16(af, W2F[(0 * 16 + kc) * 64 + lane], ap0, 0, 0, 0);
            ap1 = __builtin_amdgcn_mfma_f32_16x16x32_bf16(af, W2F[(1 * 16 + kc) * 64 + lane], ap1, 0, 0, 0);
        }
#pragma unroll
        for (int rg = 0; rg < 4; ++rg) {
            ppf[((kg * 4 + mtw) * 2 + 0) * 256 + lane * 4 + rg] = ap0[rg];
            ppf[((kg * 4 + mtw) * 2 + 1) * 256 + lane * 4 + rg] = ap1[rg];
        }
    }
    __syncthreads();  // S4: partials ready
    float llm[2];
#pragma unroll
    for (int rh = 0; rh < 2; ++rh) {
        const int slot = rh * 32 + pr;
        const int bsub = slot >> 4, toff = slot & 15;
        const int mm = slot & 15;
        const int lane_c = ((mm >> 2) * 16 + (pc & 15));
        const int rgc = mm & 3, ntv = pc >> 4;
        float pv = b2v;
#pragma unroll
        for (int kg = 0; kg < 4; ++kg)
            pv += ppf[((kg * 4 + bsub) * 2 + ntv) * 256 + lane_c * 4 + rgc];
        const int half = lane & 32;
        float meanv = __shfl(pv, half + ((pc + 10) & 31), 64);
        float lsigv = __shfl(pv, half + ((pc + 20) & 31), 64);
        float e1, e2;
        if (pc < 10) {
            float ztar = z[(size_t)(b0 + bsub) * DD + t0 + tg * 16 + toff];
            float invs = __expf(-lsigv);
            float dd = (ztar - meanv) * invs;
            e1 = -0.5f * dd * dd - lsigv - 0.91893853320467274f + pv;
            e2 = pv;
        } else { e1 = -FLT_MAX; e2 = -FLT_MAX; }
        float m1 = e1, m2 = e2;
#pragma unroll
        for (int off = 16; off > 0; off >>= 1) {
            m1 = fmaxf(m1, __shfl_xor(m1, off, 64));
            m2 = fmaxf(m2, __shfl_xor(m2, off, 64));
        }
        float s1 = (pc < 10) ? __expf(e1 - m1) : 0.0f;
        float s2 = (pc < 10) ? __expf(e2 - m2) : 0.0f;
#pragma unroll
        for (int off = 16; off > 0; off >>= 1) {
            s1 += __shfl_xor(s1, off, 64);
            s2 += __shfl_xor(s2, off, 64);
        }
        float ll = (m1 + __logf(s1)) - (m2 + __logf(s2));
        llm[rh] = ll * maskbuf[(size_t)(b0 + bsub) * DD + t0 + tg * 16 + toff];
    }
    __syncthreads();  // S5
    if (pc == 0) { ppf[pr] = llm[0]; ppf[32 + pr] = llm[1]; }
    __syncthreads();  // S6
    if (tid < 4) {
        float s = 0.0f;
#pragma unroll
        for (int j = 0; j < 16; ++j) s += ppf[tid * 16 + j];
        atomicAdd(&out[b0 + tid], s);
    }
}

// ================= FALLBACK: R5-verified fused kernel (small workspace) =================
__global__ __launch_bounds__(1024, 4) void gru_mfma_r5(
    const float* __restrict__ z, const float* __restrict__ Wih,
    const float* __restrict__ bhh, const float* __restrict__ b1,
    const float* __restrict__ b2,
    const float* __restrict__ gi_const, const float* __restrict__ mlp_const,
    const float* __restrict__ maskbuf,
    const unsigned short* __restrict__ WhhP, const unsigned short* __restrict__ W0hP,
    const unsigned short* __restrict__ W1P, const unsigned short* __restrict__ W2P,
    float* __restrict__ out)
{
    __shared__ unsigned short h_bf[16 * 520];
    __shared__ unsigned short a_bf[16 * 520];
    __shared__ float pp[16 * 512];
    __shared__ float zbuf[113 * 16];
    __shared__ float mbuf[16 * 112];

    const int tid = threadIdx.x;
    const int wave = tid >> 6, lane = tid & 63;
    const int quad = lane >> 4, l16 = lane & 15;
    const int pr = tid >> 5, pc = tid & 31;
    const int rowBase = blockIdx.x * 16;

    for (int idx = tid; idx < 16 * 520; idx += 1024) h_bf[idx] = 0;
    for (int idx = tid; idx < 113 * 16; idx += 1024) {
        int tt = idx >> 4, r = idx & 15;
        zbuf[idx] = (tt == 0) ? -1.0f : z[(rowBase + r) * DD + tt - 1];
    }
    for (int idx = tid; idx < 16 * 112; idx += 1024) {
        int r = idx / DD, tt = idx - r * DD;
        mbuf[idx] = maskbuf[(rowBase + r) * DD + tt];
    }
    int hcol[2];
    float wz0[2], wz1[2], wz2[2], bh2r[2], b1c[2];
    float gic0[2][4], gic1[2][4], gic2[2][4], mlc[2][4];
    float h_own[2][4];
#pragma unroll
    for (int i = 0; i < 2; ++i) {
        int tile = wave + 16 * i;
        int hc = tile * 16 + l16;
        hcol[i] = hc;
        wz0[i] = Wih[hc]; wz1[i] = Wih[512 + hc]; wz2[i] = Wih[1024 + hc];
        float bh0 = bhh[hc], bh1 = bhh[512 + hc];
        bh2r[i] = bhh[1024 + hc];
        b1c[i] = b1[hc];
#pragma unroll
        for (int rg = 0; rg < 4; ++rg) {
            int m = quad * 4 + rg;
            const float* g = gi_const + (size_t)(rowBase + m) * G3;
            gic0[i][rg] = g[hc] + bh0;
            gic1[i][rg] = g[512 + hc] + bh1;
            gic2[i][rg] = g[1024 + hc];
            mlc[i][rg] = mlp_const[(size_t)(rowBase + m) * HIDD + hc];
            h_own[i][rg] = 0.0f;
        }
    }
    const float b2v = (pc < 30) ? b2[pc] : 0.0f;
    const int ppbase = (pc >> 4) * 256 + ((pr >> 2) * 16 + (pc & 15)) * 4 + (pr & 3);
    const short8* WhhF = (const short8*)WhhP;
    const short8* W0hF = (const short8*)W0hP;
    const short8* W1F  = (const short8*)W1P;
    const short8* W2F  = (const short8*)W2P;
    float llacc = 0.0f;
    __syncthreads();
    for (int t = 0; t < DD; ++t) {
        float4v accR[2], accU[2], accN[2];
#pragma unroll
        for (int i = 0; i < 2; ++i) {
            accR[i] = (float4v){gic0[i][0], gic0[i][1], gic0[i][2], gic0[i][3]};
            accU[i] = (float4v){gic1[i][0], gic1[i][1], gic1[i][2], gic1[i][3]};
            accN[i] = (float4v){0.f, 0.f, 0.f, 0.f};
        }
#pragma unroll 4
        for (int kc = 0; kc < 16; ++kc) {
            short8 af = *(const short8*)&h_bf[l16 * 520 + kc * 32 + quad * 8];
#pragma unroll
            for (int i = 0; i < 2; ++i) {
                int tile = wave + 16 * i;
                accR[i] = __builtin_amdgcn_mfma_f32_16x16x32_bf16(af, WhhF[(tile * 16 + kc) * 64 + lane], accR[i], 0, 0, 0);
                accU[i] = __builtin_amdgcn_mfma_f32_16x16x32_bf16(af, WhhF[((tile + 32) * 16 + kc) * 64 + lane], accU[i], 0, 0, 0);
                accN[i] = __builtin_amdgcn_mfma_f32_16x16x32_bf16(af, WhhF[((tile + 64) * 16 + kc) * 64 + lane], accN[i], 0, 0, 0);
            }
        }
        __syncthreads();
#pragma unroll
        for (int i = 0; i < 2; ++i) {
#pragma unroll
            for (int rg = 0; rg < 4; ++rg) {
                int m = quad * 4 + rg;
                float zt = zbuf[t * 16 + m];
                float r = 1.0f / (1.0f + __expf(-(accR[i][rg] + zt * wz0[i])));
                float u = 1.0f / (1.0f + __expf(-(accU[i][rg] + zt * wz1[i])));
                float xn = gic2[i][rg] + zt * wz2[i] + r * (accN[i][rg] + bh2r[i]);
                float n = 1.0f - 2.0f / (__expf(2.0f * xn) + 1.0f);
                float h2 = (1.0f - u) * n + u * h_own[i][rg];
                h_own[i][rg] = h2;
                h_bf[m * 520 + hcol[i]] = f2bf(h2);
            }
        }
        __syncthreads();
        float4v acc1[2];
#pragma unroll
        for (int i = 0; i < 2; ++i) acc1[i] = (float4v){mlc[i][0], mlc[i][1], mlc[i][2], mlc[i][3]};
#pragma unroll 4
        for (int kc = 0; kc < 16; ++kc) {
            short8 af = *(const short8*)&h_bf[l16 * 520 + kc * 32 + quad * 8];
#pragma unroll
            for (int i = 0; i < 2; ++i)
                acc1[i] = __builtin_amdgcn_mfma_f32_16x16x32_bf16(af, W0hF[((wave + 16 * i) * 16 + kc) * 64 + lane], acc1[i], 0, 0, 0);
        }
#pragma unroll
        for (int i = 0; i < 2; ++i)
#pragma unroll
            for (int rg = 0; rg < 4; ++rg) {
                int m = quad * 4 + rg;
                float x = acc1[i][rg];
                a_bf[m * 520 + hcol[i]] = f2bf(1.0f - 2.0f / (__expf(2.0f * x) + 1.0f));
            }
        __syncthreads();
        float4v acc2[2];
#pragma unroll
        for (int i = 0; i < 2; ++i) acc2[i] = (float4v){b1c[i], b1c[i], b1c[i], b1c[i]};
#pragma unroll 4
        for (int kc = 0; kc < 16; ++kc) {
            short8 af = *(const short8*)&a_bf[l16 * 520 + kc * 32 + quad * 8];
#pragma unroll
            for (int i = 0; i < 2; ++i)
                acc2[i] = __builtin_amdgcn_mfma_f32_16x16x32_bf16(af, W1F[((wave + 16 * i) * 16 + kc) * 64 + lane], acc2[i], 0, 0, 0);
        }
        __syncthreads();
#pragma unroll
        for (int i = 0; i < 2; ++i)
#pragma unroll
            for (int rg = 0; rg < 4; ++rg) {
                int m = quad * 4 + rg;
                float x = acc2[i][rg];
                a_bf[m * 520 + hcol[i]] = f2bf(1.0f - 2.0f / (__expf(2.0f * x) + 1.0f));
            }
        __syncthreads();
        {
            int kc = wave;
            short8 af = *(const short8*)&a_bf[l16 * 520 + kc * 32 + quad * 8];
            float4v ap0 = (float4v){0.f, 0.f, 0.f, 0.f}, ap1 = (float4v){0.f, 0.f, 0.f, 0.f};
            ap0 = __builtin_amdgcn_mfma_f32_16x16x32_bf16(af, W2F[(0 * 16 + kc) * 64 + lane], ap0, 0, 0, 0);
            ap1 = __builtin_amdgcn_mfma_f32_16x16x32_bf16(af, W2F[(1 * 16 + kc) * 64 + lane], ap1, 0, 0, 0);
#pragma unroll
            for (int rg = 0; rg < 4; ++rg) {
                pp[wave * 512 + 0 * 256 + lane * 4 + rg] = ap0[rg];
                pp[wave * 512 + 1 * 256 + lane * 4 + rg] = ap1[rg];
            }
        }
        __syncthreads();
        if (wave < 8) {
            float pv = b2v;
#pragma unroll
            for (int w = 0; w < 16; ++w) pv += pp[w * 512 + ppbase];
            const int half = lane & 32;
            float meanv = __shfl(pv, half + ((pc + 10) & 31), 64);
            float lsigv = __shfl(pv, half + ((pc + 20) & 31), 64);
            float e1, e2;
            if (pc < 10) {
                float ztar = zbuf[(t + 1) * 16 + pr];
                float invs = __expf(-lsigv);
                float dd = (ztar - meanv) * invs;
                e1 = -0.5f * dd * dd - lsigv - 0.91893853320467274f + pv;
                e2 = pv;
            } else { e1 = -FLT_MAX; e2 = -FLT_MAX; }
            float m1 = e1, m2 = e2;
#pragma unroll
            for (int off = 16; off > 0; off >>= 1) {
                m1 = fmaxf(m1, __shfl_xor(m1, off, 64));
                m2 = fmaxf(m2, __shfl_xor(m2, off, 64));
            }
            float s1 = (pc < 10) ? __expf(e1 - m1) : 0.0f;
            float s2 = (pc < 10) ? __expf(e2 - m2) : 0.0f;
#pragma unroll
            for (int off = 16; off > 0; off >>= 1) {
                s1 += __shfl_xor(s1, off, 64);
                s2 += __shfl_xor(s2, off, 64);
            }
            float ll = (m1 + __logf(s1)) - (m2 + __logf(s2));
            llacc += ll * mbuf[pr * 112 + t];
        }
    }
    if (wave < 8 && pc == 0) out[rowBase + pr] = llacc;
}

extern "C" void kernel_launch(void* const* d_in, const int* in_sizes, int n_in,
                              void* d_out, int out_size, void* d_ws, size_t ws_size,
                              hipStream_t stream) {
    const float* z   = (const float*)d_in[0];
    const float* c   = (const float*)d_in[1];
    const float* b   = (const float*)d_in[2];
    const float* m   = (const float*)d_in[3];
    const float* Wih = (const float*)d_in[4];
    const float* Whh = (const float*)d_in[5];
    const float* bih = (const float*)d_in[6];
    const float* bhh = (const float*)d_in[7];
    const float* W0  = (const float*)d_in[8];
    const float* b0  = (const float*)d_in[9];
    const float* W1  = (const float*)d_in[10];
    const float* b1  = (const float*)d_in[11];
    const float* W2  = (const float*)d_in[12];
    const float* b2  = (const float*)d_in[13];
    float* out = (float*)d_out;

    char* p = (char*)d_ws;
    unsigned short* constbf = (unsigned short*)p;  p += (size_t)BN * CWP * 2;
    float* gi_const  = (float*)p;                  p += (size_t)BN * G3 * 4;
    float* mlp_const = (float*)p;                  p += (size_t)BN * HIDD * 4;
    float* maskbuf   = (float*)p;                  p += (size_t)BN * DD * 4;
    unsigned short* WihP = (unsigned short*)p;     p += (size_t)96 * 17 * 512 * 2;
    unsigned short* W0cP = (unsigned short*)p;     p += (size_t)32 * 17 * 512 * 2;
    unsigned short* WhhP = (unsigned short*)p;     p += (size_t)96 * 16 * 512 * 2;
    unsigned short* W0hP = (unsigned short*)p;     p += (size_t)32 * 16 * 512 * 2;
    unsigned short* W1P  = (unsigned short*)p;     p += (size_t)32 * 16 * 512 * 2;
    unsigned short* W2P  = (unsigned short*)p;     p += (size_t)2 * 16 * 512 * 2;
    float* hstate        = (float*)p;              p += (size_t)BN * HH * 4;
    unsigned short* h2g  = (unsigned short*)p;

    const size_t base = (size_t)(p - (char*)d_ws);
    const size_t slab_per_t = (size_t)BN * 512 * 2;
    int TC = 0;
    if (ws_size > base) {
        TC = (int)((ws_size - base) / slab_per_t);
        TC = (TC / 16) * 16;
        if (TC > DD) TC = DD;
    }

    build_constbf<<<(BN * CWP + 255) / 256, 256, 0, stream>>>(c, b, m, constbf);
    pack_wN<<<96 * 17, 64, 0, stream>>>(Wih + G3, WihP, 17, G3, G3, CW);
    pack_wN<<<32 * 17, 64, 0, stream>>>(W0 + (size_t)HH * HIDD, W0cP, 17, HIDD, HIDD, CW);
    pack_wN<<<96 * 16, 64, 0, stream>>>(Whh, WhhP, 16, G3, G3, HH);
    pack_wN<<<32 * 16, 64, 0, stream>>>(W0,  W0hP, 16, HIDD, HIDD, HH);
    pack_wN<<<32 * 16, 64, 0, stream>>>(W1,  W1P,  16, HIDD, HIDD, HH);
    pack_wN<<<2 * 16, 64, 0, stream>>>(W2,  W2P,  16, 30, 30, HH);
    gemm_const_mfma<6><<<BN / 16, 1024, 0, stream>>>(constbf, WihP, bih, gi_const, G3);
    gemm_const_mfma<2><<<BN / 16, 1024, 0, stream>>>(constbf, W0cP, b0, mlp_const, HIDD);
    sort_mask<<<BN, 128, 0, stream>>>(b, m, maskbuf);

    if (TC >= 16) {
        zero_f32<<<(BN * HH + 255) / 256, 256, 0, stream>>>(hstate, BN * HH);
        zero_f32<<<(BN + 255) / 256, 256, 0, stream>>>(out, BN);
        for (int t0 = 0; t0 < DD; t0 += TC) {
            int tlen = DD - t0 < TC ? DD - t0 : TC;
            gru_rec_chunk<<<BN / 16, 1024, 0, stream>>>(z, Wih, bhh, gi_const, WhhP,
                                                        hstate, h2g, t0, tlen);
            dim3 gh(BN / 4, tlen / 16);
            head_mdn64<<<gh, 1024, 0, stream>>>(z, b1, b2, mlp_const, maskbuf, h2g,
                                                W0hP, W1P, W2P, out, t0);
        }
    } else {
        gru_mfma_r5<<<BN / 16, 1024, 0, stream>>>(z, Wih, bhh, b1, b2, gi_const,
                                                  mlp_const, maskbuf, WhhP, W0hP, W1P, W2P, out);
    }
}